// Round 3
// baseline (379.443 us; speedup 1.0000x reference)
//
#include <hip/hip_runtime.h>
#include <hip/hip_bf16.h>

#define FIN 256
#define FH 128
#define FZ 32

typedef unsigned short u16;
typedef unsigned int u32;
typedef __attribute__((ext_vector_type(4))) float f32x4;
typedef __attribute__((ext_vector_type(8))) short bf16x8;
typedef __attribute__((ext_vector_type(4))) unsigned int uint4v;

__device__ inline u16 f2bf(float v) {
    u32 u = __float_as_uint(v);
    u32 r = (u + 0x7fffu + ((u >> 16) & 1u)) >> 16;  // RNE
    return (u16)r;
}
__device__ inline float bf2f(u16 h) { return __uint_as_float(((u32)h) << 16); }

// ---------------- CSR build ----------------
__global__ void deg_count(const int* __restrict__ dst, int* __restrict__ deg, int E) {
    int e = blockIdx.x * 256 + threadIdx.x;
    if (e < E) atomicAdd(&deg[dst[e]], 1);
}

__global__ void partial_sum(const int* __restrict__ deg, int* __restrict__ part) {
    __shared__ int s[256];
    int t = threadIdx.x;
    s[t] = deg[blockIdx.x * 256 + t];
    __syncthreads();
    for (int o = 128; o > 0; o >>= 1) {
        if (t < o) s[t] += s[t + o];
        __syncthreads();
    }
    if (t == 0) part[blockIdx.x] = s[0];
}

__global__ void scan_part(const int* __restrict__ part, int* __restrict__ poffs) {
    __shared__ int s[256];
    int t = threadIdx.x;
    int v = part[t];
    s[t] = v;
    __syncthreads();
    for (int o = 1; o < 256; o <<= 1) {
        int add = (t >= o) ? s[t - o] : 0;
        __syncthreads();
        s[t] += add;
        __syncthreads();
    }
    poffs[t] = s[t] - v;  // exclusive
}

__global__ void scan_row(const int* __restrict__ deg, const int* __restrict__ poffs,
                         int* __restrict__ rowptr, int n) {
    __shared__ int s[256];
    int t = threadIdx.x;
    int i = blockIdx.x * 256 + t;
    int v = deg[i];
    s[t] = v;
    __syncthreads();
    for (int o = 1; o < 256; o <<= 1) {
        int add = (t >= o) ? s[t - o] : 0;
        __syncthreads();
        s[t] += add;
        __syncthreads();
    }
    int incl = s[t] + poffs[blockIdx.x];
    rowptr[i] = incl - v;
    if (i == n - 1) rowptr[n] = incl;
}

__global__ void dis_k(const int* __restrict__ deg, float* __restrict__ dis, int n) {
    int i = blockIdx.x * 256 + threadIdx.x;
    if (i < n) dis[i] = rsqrtf((float)deg[i] + 1.0f);
}

__global__ void csr_fill(const int* __restrict__ src, const int* __restrict__ dst,
                         const float* __restrict__ dis, int* __restrict__ cursor,
                         int* __restrict__ csrc, float* __restrict__ cw, int E) {
    int e = blockIdx.x * 256 + threadIdx.x;
    if (e >= E) return;
    int s = src[e], d = dst[e];
    int p = atomicAdd(&cursor[d], 1);
    csrc[p] = s;
    cw[p] = dis[s] * dis[d];
}

// ---------------- weight prep: fp32 W[K][N] -> split-bf16 Wt[N][K] ----------------
__global__ void w_prep(const float* __restrict__ W, u16* __restrict__ whi,
                       u16* __restrict__ wlo, int K, int N) {
    int idx = blockIdx.x * 256 + threadIdx.x;
    if (idx >= K * N) return;
    int k = idx / N, n = idx % N;
    float v = W[idx];
    u16 hi = f2bf(v);
    u16 lo = f2bf(v - bf2f(hi));
    whi[n * K + k] = hi;
    wlo[n * K + k] = lo;
}

// ---------------- GEMM: W resident in LDS (swizzled), barrier-free main loop ----------------
// Y[M,N] = (LN? LayerNorm(X) : X)[M,K] @ W[K,N], Wt[N][K] split hi/lo.
// Block = 512 thr = 8 waves = WM x WN wave grid; each wave: 16 rows x (N/WN) cols.
template <int K, int N, bool LN>
__global__ __launch_bounds__(512) void gemm_w(
    const float* __restrict__ X, const u16* __restrict__ WhiG, const u16* __restrict__ WloG,
    const float* __restrict__ lnw, const float* __restrict__ lnb, float* __restrict__ Y,
    int mtiles) {
    constexpr int WN = (N >= 64) ? 4 : 2;
    constexpr int WM = 8 / WN;
    constexpr int BM = WM * 16;
    constexpr int NT = N / (WN * 16);
    constexpr int NC = K / 32;  // k-chunks of 32

    extern __shared__ char smem[];
    u16* Whi = (u16*)smem;            // [N][K], 8-u16 groups XOR-swizzled by (n&7)
    u16* Wlo = (u16*)(smem + (size_t)N * K * 2);

    const int t = threadIdx.x;

    // stage W once (swizzle on store; 16B chunks, coalesced reads)
    constexpr int CH = (N * K) / 8;
    for (int i = t; i < CH; i += 512) {
        int n = i / (K / 8);
        int k8 = i % (K / 8);
        int sw = ((k8 ^ (n & 7)) * 8);
        *(uint4v*)&Whi[n * K + sw] = *(const uint4v*)&WhiG[n * K + k8 * 8];
        *(uint4v*)&Wlo[n * K + sw] = *(const uint4v*)&WloG[n * K + k8 * 8];
    }
    __syncthreads();

    const int wave = t >> 6, l = t & 63;
    const int wm = wave / WN, wn = wave % WN;
    const int lm = l & 15, lq = l >> 4;

    for (int mt = blockIdx.x; mt < mtiles; mt += gridDim.x) {
        const int row = mt * BM + wm * 16 + lm;
        const float* xr = X + (long long)row * K;

        // load this lane's A slice: chunk j covers cols j*32 + lq*8 .. +7
        float v[NC * 8];
#pragma unroll
        for (int j = 0; j < NC; ++j) {
            f32x4 a0 = *(const f32x4*)(xr + j * 32 + lq * 8);
            f32x4 a1 = *(const f32x4*)(xr + j * 32 + lq * 8 + 4);
#pragma unroll
            for (int c = 0; c < 4; ++c) {
                v[j * 8 + c] = a0[c];
                v[j * 8 + 4 + c] = a1[c];
            }
        }

        float mu = 0.f, rsig = 1.f;
        if (LN) {
            float s = 0.f, ss = 0.f;
#pragma unroll
            for (int i = 0; i < NC * 8; ++i) {
                s += v[i];
                ss += v[i] * v[i];
            }
            s += __shfl_xor(s, 16);
            ss += __shfl_xor(ss, 16);
            s += __shfl_xor(s, 32);
            ss += __shfl_xor(ss, 32);
            mu = s * (1.0f / K);
            rsig = rsqrtf(ss * (1.0f / K) - mu * mu + 1e-5f);
        }

        f32x4 acc[NT];
#pragma unroll
        for (int i = 0; i < NT; ++i) acc[i] = (f32x4){0.f, 0.f, 0.f, 0.f};

#pragma unroll
        for (int kk = 0; kk < NC; ++kk) {
            f32x4 lw0, lw1, lb0, lb1;
            if (LN) {
                lw0 = *(const f32x4*)(lnw + kk * 32 + lq * 8);
                lw1 = *(const f32x4*)(lnw + kk * 32 + lq * 8 + 4);
                lb0 = *(const f32x4*)(lnb + kk * 32 + lq * 8);
                lb1 = *(const f32x4*)(lnb + kk * 32 + lq * 8 + 4);
            }
            u32 H[4], L[4];
#pragma unroll
            for (int p = 0; p < 4; ++p) {
                float x0 = v[kk * 8 + p * 2];
                float x1 = v[kk * 8 + p * 2 + 1];
                if (LN) {
                    float w0 = (p * 2 < 4) ? lw0[p * 2] : lw1[p * 2 - 4];
                    float w1 = (p * 2 + 1 < 4) ? lw0[p * 2 + 1] : lw1[p * 2 - 3];
                    float c0 = (p * 2 < 4) ? lb0[p * 2] : lb1[p * 2 - 4];
                    float c1 = (p * 2 + 1 < 4) ? lb0[p * 2 + 1] : lb1[p * 2 - 3];
                    x0 = (x0 - mu) * rsig * w0 + c0;
                    x1 = (x1 - mu) * rsig * w1 + c1;
                }
                u16 h0 = f2bf(x0), h1 = f2bf(x1);
                u16 g0 = f2bf(x0 - bf2f(h0)), g1 = f2bf(x1 - bf2f(h1));
                H[p] = (u32)h0 | ((u32)h1 << 16);
                L[p] = (u32)g0 | ((u32)g1 << 16);
            }
            uint4v Hv, Lv;
            Hv.x = H[0]; Hv.y = H[1]; Hv.z = H[2]; Hv.w = H[3];
            Lv.x = L[0]; Lv.y = L[1]; Lv.z = L[2]; Lv.w = L[3];
            bf16x8 ah = __builtin_bit_cast(bf16x8, Hv);
            bf16x8 al = __builtin_bit_cast(bf16x8, Lv);

#pragma unroll
            for (int nt = 0; nt < NT; ++nt) {
                int n = wn * (N / WN) + nt * 16 + lm;
                int off = n * K + (((kk * 4 + lq) ^ (n & 7)) * 8);
                bf16x8 bh = *(const bf16x8*)&Whi[off];
                bf16x8 bl = *(const bf16x8*)&Wlo[off];
                acc[nt] = __builtin_amdgcn_mfma_f32_16x16x32_bf16(ah, bh, acc[nt], 0, 0, 0);
                acc[nt] = __builtin_amdgcn_mfma_f32_16x16x32_bf16(ah, bl, acc[nt], 0, 0, 0);
                acc[nt] = __builtin_amdgcn_mfma_f32_16x16x32_bf16(al, bh, acc[nt], 0, 0, 0);
            }
        }

        const int mbase = mt * BM + wm * 16 + lq * 4;
#pragma unroll
        for (int nt = 0; nt < NT; ++nt) {
            int c = wn * (N / WN) + nt * 16 + lm;
#pragma unroll
            for (int r = 0; r < 4; ++r) Y[(long long)(mbase + r) * N + c] = acc[nt][r];
        }
    }
}

// ---------------- CSR gather, 4 edge-slots/wave, f32x4 x2 ----------------
__global__ __launch_bounds__(256) void agg128(
    const float* __restrict__ XW, const int* __restrict__ rowptr, const int* __restrict__ csrc,
    const float* __restrict__ cw, const float* __restrict__ dis, const float* __restrict__ bias,
    float* __restrict__ OUT, int relu) {
    int node = blockIdx.x * 4 + (threadIdx.x >> 6);
    int l = threadIdx.x & 63;
    int h = l >> 4, c = l & 15;  // 4 edge slots x 16 lanes
    float di = dis[node];
    f32x4 acc0 = (f32x4){0.f, 0.f, 0.f, 0.f};
    f32x4 acc1 = (f32x4){0.f, 0.f, 0.f, 0.f};
    if (h == 0) {
        f32x4 s0 = *(const f32x4*)(XW + (long long)node * 128 + c * 4);
        f32x4 s1 = *(const f32x4*)(XW + (long long)node * 128 + c * 4 + 64);
        f32x4 b0 = *(const f32x4*)(bias + c * 4);
        f32x4 b1 = *(const f32x4*)(bias + c * 4 + 64);
        float d2 = di * di;
#pragma unroll
        for (int i = 0; i < 4; ++i) {
            acc0[i] = s0[i] * d2 + b0[i];
            acc1[i] = s1[i] * d2 + b1[i];
        }
    }
    int e0 = rowptr[node], e1 = rowptr[node + 1];
    int e = e0 + h;
    for (; e + 4 < e1; e += 8) {
        int s0 = csrc[e], s1 = csrc[e + 4];
        float w0 = cw[e], w1 = cw[e + 4];
        f32x4 u0 = *(const f32x4*)(XW + (long long)s0 * 128 + c * 4);
        f32x4 u1 = *(const f32x4*)(XW + (long long)s0 * 128 + c * 4 + 64);
        f32x4 t0 = *(const f32x4*)(XW + (long long)s1 * 128 + c * 4);
        f32x4 t1 = *(const f32x4*)(XW + (long long)s1 * 128 + c * 4 + 64);
#pragma unroll
        for (int i = 0; i < 4; ++i) {
            acc0[i] += u0[i] * w0 + t0[i] * w1;
            acc1[i] += u1[i] * w0 + t1[i] * w1;
        }
    }
    if (e < e1) {
        int s0 = csrc[e];
        float w0 = cw[e];
        f32x4 u0 = *(const f32x4*)(XW + (long long)s0 * 128 + c * 4);
        f32x4 u1 = *(const f32x4*)(XW + (long long)s0 * 128 + c * 4 + 64);
#pragma unroll
        for (int i = 0; i < 4; ++i) {
            acc0[i] += u0[i] * w0;
            acc1[i] += u1[i] * w0;
        }
    }
#pragma unroll
    for (int m = 16; m <= 32; m <<= 1) {
#pragma unroll
        for (int i = 0; i < 4; ++i) {
            acc0[i] += __shfl_xor(acc0[i], m);
            acc1[i] += __shfl_xor(acc1[i], m);
        }
    }
    if (h == 0) {
        if (relu) {
#pragma unroll
            for (int i = 0; i < 4; ++i) {
                acc0[i] = fmaxf(acc0[i], 0.f);
                acc1[i] = fmaxf(acc1[i], 0.f);
            }
        }
        *(f32x4*)(OUT + (long long)node * 128 + c * 4) = acc0;
        *(f32x4*)(OUT + (long long)node * 128 + c * 4 + 64) = acc1;
    }
}

// ---------------- F=32 gather: 8 edge-slots/wave ----------------
__global__ __launch_bounds__(256) void agg32(
    const float* __restrict__ XW, const int* __restrict__ rowptr, const int* __restrict__ csrc,
    const float* __restrict__ cw, const float* __restrict__ dis, const float* __restrict__ bias,
    float* __restrict__ OUT) {
    int node = blockIdx.x * 4 + (threadIdx.x >> 6);
    int l = threadIdx.x & 63;
    int h = l >> 3, c = l & 7;  // 8 edge slots x 8 lanes
    float di = dis[node];
    f32x4 acc = (f32x4){0.f, 0.f, 0.f, 0.f};
    if (h == 0) {
        f32x4 s0 = *(const f32x4*)(XW + (long long)node * 32 + c * 4);
        f32x4 b0 = *(const f32x4*)(bias + c * 4);
        float d2 = di * di;
#pragma unroll
        for (int i = 0; i < 4; ++i) acc[i] = s0[i] * d2 + b0[i];
    }
    int e0 = rowptr[node], e1 = rowptr[node + 1];
    int e = e0 + h;
    for (; e + 8 < e1; e += 16) {
        int s0 = csrc[e], s1 = csrc[e + 8];
        float w0 = cw[e], w1 = cw[e + 8];
        f32x4 u0 = *(const f32x4*)(XW + (long long)s0 * 32 + c * 4);
        f32x4 u1 = *(const f32x4*)(XW + (long long)s1 * 32 + c * 4);
#pragma unroll
        for (int i = 0; i < 4; ++i) acc[i] += u0[i] * w0 + u1[i] * w1;
    }
    if (e < e1) {
        int s0 = csrc[e];
        float w0 = cw[e];
        f32x4 u0 = *(const f32x4*)(XW + (long long)s0 * 32 + c * 4);
#pragma unroll
        for (int i = 0; i < 4; ++i) acc[i] += u0[i] * w0;
    }
#pragma unroll
    for (int m = 8; m <= 32; m <<= 1) {
#pragma unroll
        for (int i = 0; i < 4; ++i) acc[i] += __shfl_xor(acc[i], m);
    }
    if (h == 0) *(f32x4*)(OUT + (long long)node * 32 + c * 4) = acc;
}

extern "C" void kernel_launch(void* const* d_in, const int* in_sizes, int n_in,
                              void* d_out, int out_size, void* d_ws, size_t ws_size,
                              hipStream_t stream) {
    const float* x = (const float*)d_in[0];
    const int* ei = (const int*)d_in[1];
    const float* lnw = (const float*)d_in[2];
    const float* lnb = (const float*)d_in[3];
    const float* W1 = (const float*)d_in[4];
    const float* b1 = (const float*)d_in[5];
    const float* W2 = (const float*)d_in[6];
    const float* b2 = (const float*)d_in[7];
    const float* W3 = (const float*)d_in[8];
    const float* b3 = (const float*)d_in[9];
    float* out = (float*)d_out;

    const int n = in_sizes[0] / FIN;  // 65536
    const int E = in_sizes[1] / 2;    // 524288
    const int* src = ei;
    const int* dst = ei + E;

    char* w = (char*)d_ws;
    auto alloc = [&](size_t bytes) {
        char* p = w;
        w += (bytes + 255) & ~(size_t)255;
        return p;
    };
    int* deg = (int*)alloc((size_t)n * 4);
    int* rowp = (int*)alloc((size_t)(n + 1) * 4);
    int* cur = (int*)alloc((size_t)n * 4);
    int* part = (int*)alloc(256 * 4);
    int* poffs = (int*)alloc(256 * 4);
    float* dis = (float*)alloc((size_t)n * 4);
    int* csrc = (int*)alloc((size_t)E * 4);
    float* cwt = (float*)alloc((size_t)E * 4);
    u16* w1h = (u16*)alloc(FIN * FH * 2);
    u16* w1l = (u16*)alloc(FIN * FH * 2);
    u16* w2h = (u16*)alloc(FH * FH * 2);
    u16* w2l = (u16*)alloc(FH * FH * 2);
    u16* w3h = (u16*)alloc(FH * FZ * 2);
    u16* w3l = (u16*)alloc(FH * FZ * 2);
    float* bufA = (float*)alloc((size_t)n * FH * 4);
    float* bufB = (float*)alloc((size_t)n * FH * 4);

    // ---- CSR build ----
    hipMemsetAsync(deg, 0, (size_t)n * 4, stream);
    deg_count<<<E / 256, 256, 0, stream>>>(dst, deg, E);
    partial_sum<<<n / 256, 256, 0, stream>>>(deg, part);
    scan_part<<<1, 256, 0, stream>>>(part, poffs);
    scan_row<<<n / 256, 256, 0, stream>>>(deg, poffs, rowp, n);
    dis_k<<<n / 256, 256, 0, stream>>>(deg, dis, n);
    hipMemcpyAsync(cur, rowp, (size_t)n * 4, hipMemcpyDeviceToDevice, stream);
    csr_fill<<<E / 256, 256, 0, stream>>>(src, dst, dis, cur, csrc, cwt, E);

    // ---- weight prep ----
    w_prep<<<(FIN * FH + 255) / 256, 256, 0, stream>>>(W1, w1h, w1l, FIN, FH);
    w_prep<<<(FH * FH + 255) / 256, 256, 0, stream>>>(W2, w2h, w2l, FH, FH);
    w_prep<<<(FH * FZ + 255) / 256, 256, 0, stream>>>(W3, w3h, w3l, FH, FZ);

    // ---- dynamic LDS opt-in ----
    const int lds1 = FIN * FH * 4;  // 128 KiB
    const int lds2 = FH * FH * 4;   // 64 KiB
    const int lds3 = FH * FZ * 4;   // 16 KiB
    hipFuncSetAttribute((const void*)&gemm_w<256, 128, true>,
                        hipFuncAttributeMaxDynamicSharedMemorySize, lds1);
    hipFuncSetAttribute((const void*)&gemm_w<128, 128, false>,
                        hipFuncAttributeMaxDynamicSharedMemorySize, lds2);
    hipFuncSetAttribute((const void*)&gemm_w<128, 32, false>,
                        hipFuncAttributeMaxDynamicSharedMemorySize, lds3);

    // ---- conv1: LN + GEMM -> gather ----
    gemm_w<256, 128, true><<<512, 512, lds1, stream>>>(x, w1h, w1l, lnw, lnb, bufA, n / 32);
    agg128<<<n / 4, 256, 0, stream>>>(bufA, rowp, csrc, cwt, dis, b1, bufB, 1);

    // ---- conv2 ----
    gemm_w<128, 128, false><<<512, 512, lds2, stream>>>(bufB, w2h, w2l, nullptr, nullptr, bufA, n / 32);
    agg128<<<n / 4, 256, 0, stream>>>(bufA, rowp, csrc, cwt, dis, b2, bufB, 1);

    // ---- conv3 ----
    gemm_w<128, 32, false><<<512, 512, lds3, stream>>>(bufB, w3h, w3l, nullptr, nullptr, bufA, n / 64);
    agg32<<<n / 4, 256, 0, stream>>>(bufA, rowp, csrc, cwt, dis, b3, out);
}

// Round 4
// 240.508 us; speedup vs baseline: 1.5777x; 1.5777x over previous
//
#include <hip/hip_runtime.h>
#include <hip/hip_bf16.h>

#define FIN 256
#define FH 128
#define FZ 32

typedef unsigned short u16;
typedef unsigned int u32;
typedef __attribute__((ext_vector_type(4))) float f32x4;
typedef __attribute__((ext_vector_type(2))) float f32x2;
typedef __attribute__((ext_vector_type(8))) short bf16x8;
typedef __attribute__((ext_vector_type(4))) unsigned int uint4v;

__device__ inline u16 f2bf(float v) {
    u32 u = __float_as_uint(v);
    u32 r = (u + 0x7fffu + ((u >> 16) & 1u)) >> 16;  // RNE
    return (u16)r;
}
__device__ inline float bf2f(u16 h) { return __uint_as_float(((u32)h) << 16); }

// ---------------- CSR build ----------------
__global__ void deg_count(const int* __restrict__ dst, int* __restrict__ deg, int E) {
    int e = blockIdx.x * 256 + threadIdx.x;
    if (e < E) atomicAdd(&deg[dst[e]], 1);
}

__global__ void partial_sum(const int* __restrict__ deg, int* __restrict__ part) {
    __shared__ int s[256];
    int t = threadIdx.x;
    s[t] = deg[blockIdx.x * 256 + t];
    __syncthreads();
    for (int o = 128; o > 0; o >>= 1) {
        if (t < o) s[t] += s[t + o];
        __syncthreads();
    }
    if (t == 0) part[blockIdx.x] = s[0];
}

__global__ void scan_part(const int* __restrict__ part, int* __restrict__ poffs) {
    __shared__ int s[256];
    int t = threadIdx.x;
    int v = part[t];
    s[t] = v;
    __syncthreads();
    for (int o = 1; o < 256; o <<= 1) {
        int add = (t >= o) ? s[t - o] : 0;
        __syncthreads();
        s[t] += add;
        __syncthreads();
    }
    poffs[t] = s[t] - v;  // exclusive
}

// row scan + write rowptr, cursor copy, dis  (fused)
__global__ void scan_row(const int* __restrict__ deg, const int* __restrict__ poffs,
                         int* __restrict__ rowptr, int* __restrict__ cur,
                         float* __restrict__ dis, int n) {
    __shared__ int s[256];
    int t = threadIdx.x;
    int i = blockIdx.x * 256 + t;
    int v = deg[i];
    s[t] = v;
    __syncthreads();
    for (int o = 1; o < 256; o <<= 1) {
        int add = (t >= o) ? s[t - o] : 0;
        __syncthreads();
        s[t] += add;
        __syncthreads();
    }
    int incl = s[t] + poffs[blockIdx.x];
    int excl = incl - v;
    rowptr[i] = excl;
    cur[i] = excl;
    dis[i] = rsqrtf((float)v + 1.0f);
    if (i == n - 1) rowptr[n] = incl;
}

__global__ void csr_fill(const int* __restrict__ src, const int* __restrict__ dst,
                         const float* __restrict__ dis, int* __restrict__ cursor,
                         int* __restrict__ csrc, float* __restrict__ cw, int E) {
    int e = blockIdx.x * 256 + threadIdx.x;
    if (e >= E) return;
    int s = src[e], d = dst[e];
    int p = atomicAdd(&cursor[d], 1);
    csrc[p] = s;
    cw[p] = dis[s] * dis[d];
}

// ---------------- weight prep (all 3): fp32 W[K][N] -> bf16 Wt[N][K] ----------------
__global__ void w_prep_all(const float* __restrict__ W1, const float* __restrict__ W2,
                           const float* __restrict__ W3, u16* __restrict__ w1h,
                           u16* __restrict__ w2h, u16* __restrict__ w3h) {
    int i = blockIdx.x * 256 + threadIdx.x;
    if (i < FIN * FH) {
        int k = i / FH, n = i % FH;
        w1h[n * FIN + k] = f2bf(W1[i]);
    } else if (i < FIN * FH + FH * FH) {
        int j = i - FIN * FH;
        int k = j / FH, n = j % FH;
        w2h[n * FH + k] = f2bf(W2[j]);
    } else {
        int j = i - (FIN * FH + FH * FH);
        int k = j / FZ, n = j % FZ;
        w3h[n * FH + k] = f2bf(W3[j]);
    }
}

// ---------------- GEMM v2: W LDS-resident (once), per-K-step A loads, split-A x bf16-W ----------------
// Y[M,N] = (LN? LayerNorm(X) : X)[M,K] @ W[K,N].  Wt[N][K] bf16, XOR-swizzled in LDS.
// Block = 512 thr = 8 waves; BM=128 rows (16/wave); each wave does full N.
template <int K, int N, bool LN>
__global__ __launch_bounds__(512) void gemm_v2(
    const float* __restrict__ X, const u16* __restrict__ WhiG,
    const float* __restrict__ lnw, const float* __restrict__ lnb, float* __restrict__ Y) {
    constexpr int BM = 128;
    constexpr int NT = N / 16;

    extern __shared__ char smem[];
    u16* Wl = (u16*)smem;                                   // [N*K] swizzled bf16
    float* stats = (float*)(smem + (size_t)N * K * 2);      // [BM][2] (LN only)
    float* lnwl = stats + (LN ? BM * 2 : 0);                // [K]
    float* lnbl = lnwl + (LN ? K : 0);                      // [K]

    const int t = threadIdx.x;
    const int row0 = blockIdx.x * BM;

    // stage W once: chunk i -> (n, k8); swizzle k8 by n&7 (16B granules)
    for (int i = t; i < N * K / 8; i += 512) {
        int n = i / (K / 8), k8 = i % (K / 8);
        *(uint4v*)&Wl[n * K + ((k8 ^ (n & 7)) * 8)] = *(const uint4v*)&WhiG[n * K + k8 * 8];
    }

    if (LN) {
        if (t < K / 4) {
            *(f32x4*)&lnwl[t * 4] = *(const f32x4*)&lnw[t * 4];
            *(f32x4*)&lnbl[t * 4] = *(const f32x4*)&lnb[t * 4];
        }
        // per-row stats: 4 threads/row, coalesced-ish quarters
        int r = t >> 2, q = t & 3;
        const float* xr = X + (long long)(row0 + r) * K + q * (K / 4);
        float s = 0.f, ss = 0.f;
#pragma unroll
        for (int j = 0; j < K / 16; ++j) {
            f32x4 f = *(const f32x4*)(xr + j * 4);
#pragma unroll
            for (int c = 0; c < 4; ++c) {
                s += f[c];
                ss += f[c] * f[c];
            }
        }
        s += __shfl_xor(s, 1);
        ss += __shfl_xor(ss, 1);
        s += __shfl_xor(s, 2);
        ss += __shfl_xor(ss, 2);
        if (q == 0) {
            float mu = s * (1.0f / K);
            float var = ss * (1.0f / K) - mu * mu;
            stats[r * 2] = mu;
            stats[r * 2 + 1] = rsqrtf(fmaxf(var, 0.f) + 1e-5f);
        }
    }
    __syncthreads();

    const int wave = t >> 6, l = t & 63;
    const int lm = l & 15, lq = l >> 4;
    const int row = row0 + wave * 16 + lm;
    const float* xr = X + (long long)row * K;

    float mu = 0.f, rs = 1.f;
    if (LN) {
        mu = stats[(wave * 16 + lm) * 2];
        rs = stats[(wave * 16 + lm) * 2 + 1];
    }

    f32x4 acc[NT];
#pragma unroll
    for (int i = 0; i < NT; ++i) acc[i] = (f32x4){0.f, 0.f, 0.f, 0.f};

#pragma unroll 2
    for (int kk = 0; kk < K / 32; ++kk) {
        f32x4 a0 = *(const f32x4*)(xr + kk * 32 + lq * 8);
        f32x4 a1 = *(const f32x4*)(xr + kk * 32 + lq * 8 + 4);
        if (LN) {
            f32x4 w0 = *(const f32x4*)&lnwl[kk * 32 + lq * 8];
            f32x4 w1 = *(const f32x4*)&lnwl[kk * 32 + lq * 8 + 4];
            f32x4 c0 = *(const f32x4*)&lnbl[kk * 32 + lq * 8];
            f32x4 c1 = *(const f32x4*)&lnbl[kk * 32 + lq * 8 + 4];
#pragma unroll
            for (int c = 0; c < 4; ++c) {
                a0[c] = (a0[c] - mu) * rs * w0[c] + c0[c];
                a1[c] = (a1[c] - mu) * rs * w1[c] + c1[c];
            }
        }
        u32 H[4], L[4];
#pragma unroll
        for (int p = 0; p < 4; ++p) {
            float x0 = (p < 2) ? a0[p * 2] : a1[p * 2 - 4];
            float x1 = (p < 2) ? a0[p * 2 + 1] : a1[p * 2 - 3];
            u16 h0 = f2bf(x0), h1 = f2bf(x1);
            u16 g0 = f2bf(x0 - bf2f(h0)), g1 = f2bf(x1 - bf2f(h1));
            H[p] = (u32)h0 | ((u32)h1 << 16);
            L[p] = (u32)g0 | ((u32)g1 << 16);
        }
        uint4v Hv, Lv;
        Hv.x = H[0]; Hv.y = H[1]; Hv.z = H[2]; Hv.w = H[3];
        Lv.x = L[0]; Lv.y = L[1]; Lv.z = L[2]; Lv.w = L[3];
        bf16x8 ah = __builtin_bit_cast(bf16x8, Hv);
        bf16x8 al = __builtin_bit_cast(bf16x8, Lv);

#pragma unroll
        for (int nt = 0; nt < NT; ++nt) {
            int n = nt * 16 + lm;
            int off = n * K + (((kk * 4 + lq) ^ (lm & 7)) * 8);
            bf16x8 bh = *(const bf16x8*)&Wl[off];
            acc[nt] = __builtin_amdgcn_mfma_f32_16x16x32_bf16(ah, bh, acc[nt], 0, 0, 0);
            acc[nt] = __builtin_amdgcn_mfma_f32_16x16x32_bf16(al, bh, acc[nt], 0, 0, 0);
        }
    }

    const int mbase = row0 + wave * 16 + lq * 4;
#pragma unroll
    for (int nt = 0; nt < NT; ++nt) {
        int c = nt * 16 + lm;
#pragma unroll
        for (int r = 0; r < 4; ++r) Y[(long long)(mbase + r) * N + c] = acc[nt][r];
    }
}

// ---------------- CSR gather, 4 edge-slots/wave, f32x4 x2 ----------------
__global__ __launch_bounds__(256) void agg128(
    const float* __restrict__ XW, const int* __restrict__ rowptr, const int* __restrict__ csrc,
    const float* __restrict__ cw, const float* __restrict__ dis, const float* __restrict__ bias,
    float* __restrict__ OUT, int relu) {
    int node = blockIdx.x * 4 + (threadIdx.x >> 6);
    int l = threadIdx.x & 63;
    int h = l >> 4, c = l & 15;  // 4 edge slots x 16 lanes
    float di = dis[node];
    f32x4 acc0 = (f32x4){0.f, 0.f, 0.f, 0.f};
    f32x4 acc1 = (f32x4){0.f, 0.f, 0.f, 0.f};
    if (h == 0) {
        f32x4 s0 = *(const f32x4*)(XW + (long long)node * 128 + c * 4);
        f32x4 s1 = *(const f32x4*)(XW + (long long)node * 128 + c * 4 + 64);
        f32x4 b0 = *(const f32x4*)(bias + c * 4);
        f32x4 b1 = *(const f32x4*)(bias + c * 4 + 64);
        float d2 = di * di;
#pragma unroll
        for (int i = 0; i < 4; ++i) {
            acc0[i] = s0[i] * d2 + b0[i];
            acc1[i] = s1[i] * d2 + b1[i];
        }
    }
    int e1 = rowptr[node + 1];
    int e = rowptr[node] + h;
    for (; e + 4 < e1; e += 8) {
        int s0 = csrc[e], s1 = csrc[e + 4];
        float w0 = cw[e], w1 = cw[e + 4];
        f32x4 u0 = *(const f32x4*)(XW + (long long)s0 * 128 + c * 4);
        f32x4 u1 = *(const f32x4*)(XW + (long long)s0 * 128 + c * 4 + 64);
        f32x4 t0 = *(const f32x4*)(XW + (long long)s1 * 128 + c * 4);
        f32x4 t1 = *(const f32x4*)(XW + (long long)s1 * 128 + c * 4 + 64);
#pragma unroll
        for (int i = 0; i < 4; ++i) {
            acc0[i] += u0[i] * w0 + t0[i] * w1;
            acc1[i] += u1[i] * w0 + t1[i] * w1;
        }
    }
    if (e < e1) {
        int s0 = csrc[e];
        float w0 = cw[e];
        f32x4 u0 = *(const f32x4*)(XW + (long long)s0 * 128 + c * 4);
        f32x4 u1 = *(const f32x4*)(XW + (long long)s0 * 128 + c * 4 + 64);
#pragma unroll
        for (int i = 0; i < 4; ++i) {
            acc0[i] += u0[i] * w0;
            acc1[i] += u1[i] * w0;
        }
    }
#pragma unroll
    for (int m = 16; m <= 32; m <<= 1) {
#pragma unroll
        for (int i = 0; i < 4; ++i) {
            acc0[i] += __shfl_xor(acc0[i], m);
            acc1[i] += __shfl_xor(acc1[i], m);
        }
    }
    if (h == 0) {
        if (relu) {
#pragma unroll
            for (int i = 0; i < 4; ++i) {
                acc0[i] = fmaxf(acc0[i], 0.f);
                acc1[i] = fmaxf(acc1[i], 0.f);
            }
        }
        *(f32x4*)(OUT + (long long)node * 128 + c * 4) = acc0;
        *(f32x4*)(OUT + (long long)node * 128 + c * 4 + 64) = acc1;
    }
}

// ---------------- F=32 gather: 8 edge-slots/wave ----------------
__global__ __launch_bounds__(256) void agg32(
    const float* __restrict__ XW, const int* __restrict__ rowptr, const int* __restrict__ csrc,
    const float* __restrict__ cw, const float* __restrict__ dis, const float* __restrict__ bias,
    float* __restrict__ OUT) {
    int node = blockIdx.x * 4 + (threadIdx.x >> 6);
    int l = threadIdx.x & 63;
    int h = l >> 3, c = l & 7;  // 8 edge slots x 8 lanes
    float di = dis[node];
    f32x4 acc = (f32x4){0.f, 0.f, 0.f, 0.f};
    if (h == 0) {
        f32x4 s0 = *(const f32x4*)(XW + (long long)node * 32 + c * 4);
        f32x4 b0 = *(const f32x4*)(bias + c * 4);
        float d2 = di * di;
#pragma unroll
        for (int i = 0; i < 4; ++i) acc[i] = s0[i] * d2 + b0[i];
    }
    int e1 = rowptr[node + 1];
    int e = rowptr[node] + h;
    for (; e + 8 < e1; e += 16) {
        int s0 = csrc[e], s1 = csrc[e + 8];
        float w0 = cw[e], w1 = cw[e + 8];
        f32x4 u0 = *(const f32x4*)(XW + (long long)s0 * 32 + c * 4);
        f32x4 u1 = *(const f32x4*)(XW + (long long)s1 * 32 + c * 4);
#pragma unroll
        for (int i = 0; i < 4; ++i) acc[i] += u0[i] * w0 + u1[i] * w1;
    }
    if (e < e1) {
        int s0 = csrc[e];
        float w0 = cw[e];
        f32x4 u0 = *(const f32x4*)(XW + (long long)s0 * 32 + c * 4);
#pragma unroll
        for (int i = 0; i < 4; ++i) acc[i] += u0[i] * w0;
    }
#pragma unroll
    for (int m = 8; m <= 32; m <<= 1) {
#pragma unroll
        for (int i = 0; i < 4; ++i) acc[i] += __shfl_xor(acc[i], m);
    }
    if (h == 0) *(f32x4*)(OUT + (long long)node * 32 + c * 4) = acc;
}

extern "C" void kernel_launch(void* const* d_in, const int* in_sizes, int n_in,
                              void* d_out, int out_size, void* d_ws, size_t ws_size,
                              hipStream_t stream) {
    const float* x = (const float*)d_in[0];
    const int* ei = (const int*)d_in[1];
    const float* lnw = (const float*)d_in[2];
    const float* lnb = (const float*)d_in[3];
    const float* W1 = (const float*)d_in[4];
    const float* b1 = (const float*)d_in[5];
    const float* W2 = (const float*)d_in[6];
    const float* b2 = (const float*)d_in[7];
    const float* W3 = (const float*)d_in[8];
    const float* b3 = (const float*)d_in[9];
    float* out = (float*)d_out;

    const int n = in_sizes[0] / FIN;  // 65536
    const int E = in_sizes[1] / 2;    // 524288
    const int* src = ei;
    const int* dst = ei + E;

    char* w = (char*)d_ws;
    auto alloc = [&](size_t bytes) {
        char* p = w;
        w += (bytes + 255) & ~(size_t)255;
        return p;
    };
    int* deg = (int*)alloc((size_t)n * 4);
    int* rowp = (int*)alloc((size_t)(n + 1) * 4);
    int* cur = (int*)alloc((size_t)n * 4);
    int* part = (int*)alloc(256 * 4);
    int* poffs = (int*)alloc(256 * 4);
    float* dis = (float*)alloc((size_t)n * 4);
    int* csrc = (int*)alloc((size_t)E * 4);
    float* cwt = (float*)alloc((size_t)E * 4);
    u16* w1h = (u16*)alloc(FIN * FH * 2);
    u16* w2h = (u16*)alloc(FH * FH * 2);
    u16* w3h = (u16*)alloc(FH * FZ * 2);
    float* bufA = (float*)alloc((size_t)n * FH * 4);
    float* bufB = (float*)alloc((size_t)n * FH * 4);

    // ---- CSR build ----
    hipMemsetAsync(deg, 0, (size_t)n * 4, stream);
    deg_count<<<E / 256, 256, 0, stream>>>(dst, deg, E);
    partial_sum<<<n / 256, 256, 0, stream>>>(deg, part);
    scan_part<<<1, 256, 0, stream>>>(part, poffs);
    scan_row<<<n / 256, 256, 0, stream>>>(deg, poffs, rowp, cur, dis, n);
    csr_fill<<<E / 256, 256, 0, stream>>>(src, dst, dis, cur, csrc, cwt, E);

    // ---- weight prep (fused, hi only) ----
    w_prep_all<<<(FIN * FH + FH * FH + FH * FZ) / 256, 256, 0, stream>>>(W1, W2, W3, w1h, w2h, w3h);

    // ---- dynamic LDS opt-in ----
    const int lds1 = FIN * FH * 2 + 128 * 2 * 4 + 2 * FIN * 4;  // 68608
    const int lds2 = FH * FH * 2;                               // 32768
    const int lds3 = FZ * FH * 2;                               // 8192
    hipFuncSetAttribute((const void*)&gemm_v2<256, 128, true>,
                        hipFuncAttributeMaxDynamicSharedMemorySize, lds1);
    hipFuncSetAttribute((const void*)&gemm_v2<128, 128, false>,
                        hipFuncAttributeMaxDynamicSharedMemorySize, lds2);
    hipFuncSetAttribute((const void*)&gemm_v2<128, 32, false>,
                        hipFuncAttributeMaxDynamicSharedMemorySize, lds3);

    // ---- conv1: LN + GEMM -> gather ----
    gemm_v2<256, 128, true><<<n / 128, 512, lds1, stream>>>(x, w1h, lnw, lnb, bufA);
    agg128<<<n / 4, 256, 0, stream>>>(bufA, rowp, csrc, cwt, dis, b1, bufB, 1);

    // ---- conv2 ----
    gemm_v2<128, 128, false><<<n / 128, 512, lds2, stream>>>(bufB, w2h, nullptr, nullptr, bufA);
    agg128<<<n / 4, 256, 0, stream>>>(bufA, rowp, csrc, cwt, dis, b2, bufB, 1);

    // ---- conv3 ----
    gemm_v2<128, 32, false><<<n / 128, 512, lds3, stream>>>(bufB, w3h, nullptr, nullptr, bufA);
    agg32<<<n / 4, 256, 0, stream>>>(bufA, rowp, csrc, cwt, dis, b3, out);
}

// Round 5
// 205.186 us; speedup vs baseline: 1.8493x; 1.1721x over previous
//
#include <hip/hip_runtime.h>
#include <hip/hip_bf16.h>

#define FIN 256
#define FH 128
#define FZ 32

typedef unsigned short u16;
typedef unsigned int u32;
typedef __attribute__((ext_vector_type(4))) float f32x4;
typedef __attribute__((ext_vector_type(8))) _Float16 f16x8;
typedef __attribute__((ext_vector_type(4))) _Float16 f16x4;
typedef __attribute__((ext_vector_type(4))) unsigned int uint4v;

__device__ inline u16 f2h(float v) { return __builtin_bit_cast(u16, (_Float16)v); }

// ---------------- CSR build ----------------
__global__ void deg_count(const int* __restrict__ dst, int* __restrict__ deg, int E) {
    int e = blockIdx.x * 256 + threadIdx.x;
    if (e < E) atomicAdd(&deg[dst[e]], 1);
}

__global__ void partial_sum(const int* __restrict__ deg, int* __restrict__ part) {
    __shared__ int s[256];
    int t = threadIdx.x;
    s[t] = deg[blockIdx.x * 256 + t];
    __syncthreads();
    for (int o = 128; o > 0; o >>= 1) {
        if (t < o) s[t] += s[t + o];
        __syncthreads();
    }
    if (t == 0) part[blockIdx.x] = s[0];
}

__global__ void scan_part(const int* __restrict__ part, int* __restrict__ poffs) {
    __shared__ int s[256];
    int t = threadIdx.x;
    int v = part[t];
    s[t] = v;
    __syncthreads();
    for (int o = 1; o < 256; o <<= 1) {
        int add = (t >= o) ? s[t - o] : 0;
        __syncthreads();
        s[t] += add;
        __syncthreads();
    }
    poffs[t] = s[t] - v;  // exclusive
}

// row scan + rowptr + cursor + dis (fused)
__global__ void scan_row(const int* __restrict__ deg, const int* __restrict__ poffs,
                         int* __restrict__ rowptr, int* __restrict__ cur,
                         float* __restrict__ dis, int n) {
    __shared__ int s[256];
    int t = threadIdx.x;
    int i = blockIdx.x * 256 + t;
    int v = deg[i];
    s[t] = v;
    __syncthreads();
    for (int o = 1; o < 256; o <<= 1) {
        int add = (t >= o) ? s[t - o] : 0;
        __syncthreads();
        s[t] += add;
        __syncthreads();
    }
    int incl = s[t] + poffs[blockIdx.x];
    int excl = incl - v;
    rowptr[i] = excl;
    cur[i] = excl;
    dis[i] = rsqrtf((float)v + 1.0f);
    if (i == n - 1) rowptr[n] = incl;
}

__global__ void csr_fill(const int* __restrict__ src, const int* __restrict__ dst,
                         const float* __restrict__ dis, int* __restrict__ cursor,
                         int* __restrict__ csrc, float* __restrict__ cw, int E) {
    int e = blockIdx.x * 256 + threadIdx.x;
    if (e >= E) return;
    int s = src[e], d = dst[e];
    int p = atomicAdd(&cursor[d], 1);
    csrc[p] = s;
    cw[p] = dis[s] * dis[d];
}

// ---------------- weight prep (all 3): fp32 W[K][N] -> fp16 Wt[N][K] ----------------
__global__ void w_prep_all(const float* __restrict__ W1, const float* __restrict__ W2,
                           const float* __restrict__ W3, u16* __restrict__ w1h,
                           u16* __restrict__ w2h, u16* __restrict__ w3h) {
    int i = blockIdx.x * 256 + threadIdx.x;
    if (i < FIN * FH) {
        int k = i / FH, n = i % FH;
        w1h[n * FIN + k] = f2h(W1[i]);
    } else if (i < FIN * FH + FH * FH) {
        int j = i - FIN * FH;
        int k = j / FH, n = j % FH;
        w2h[n * FH + k] = f2h(W2[j]);
    } else {
        int j = i - (FIN * FH + FH * FH);
        int k = j / FZ, n = j % FZ;
        w3h[n * FH + k] = f2h(W3[j]);
    }
}

// ---------------- GEMM v3: fp16 MFMA, W LDS-resident (XOR-swizzled), fp16 output ----------------
// Y[M,N](fp16) = (LN? LayerNorm(Xf) : Xh)[M,K] @ W[K,N].
// Block = 512 thr = 8 waves; BM=128 rows (16/wave); each wave does full N.
template <int K, int N, bool LN>
__global__ __launch_bounds__(512) void gemm_v3(
    const float* __restrict__ Xf, const u16* __restrict__ Xh, const u16* __restrict__ Wg,
    const float* __restrict__ lnw, const float* __restrict__ lnb, u16* __restrict__ Y) {
    constexpr int BM = 128;
    constexpr int NT = N / 16;

    extern __shared__ char smem[];
    u16* Wl = (u16*)smem;                               // [N*K] swizzled f16
    float* stats = (float*)(smem + (size_t)N * K * 2);  // [BM][2] (LN only)
    float* lnwl = stats + (LN ? BM * 2 : 0);            // [K]
    float* lnbl = lnwl + (LN ? K : 0);                  // [K]

    const int t = threadIdx.x;
    const int row0 = blockIdx.x * BM;

    // stage W once: 16B granules, swizzle k8 by n&7
    for (int i = t; i < N * K / 8; i += 512) {
        int n = i / (K / 8), k8 = i % (K / 8);
        *(uint4v*)&Wl[n * K + ((k8 ^ (n & 7)) * 8)] = *(const uint4v*)&Wg[n * K + k8 * 8];
    }

    if (LN) {
        if (t < K / 4) {
            *(f32x4*)&lnwl[t * 4] = *(const f32x4*)&lnw[t * 4];
            *(f32x4*)&lnbl[t * 4] = *(const f32x4*)&lnb[t * 4];
        }
        int r = t >> 2, q = t & 3;
        const float* xr = Xf + (long long)(row0 + r) * K + q * (K / 4);
        float s = 0.f, ss = 0.f;
#pragma unroll
        for (int j = 0; j < K / 16; ++j) {
            f32x4 f = *(const f32x4*)(xr + j * 4);
#pragma unroll
            for (int c = 0; c < 4; ++c) {
                s += f[c];
                ss += f[c] * f[c];
            }
        }
        s += __shfl_xor(s, 1);
        ss += __shfl_xor(ss, 1);
        s += __shfl_xor(s, 2);
        ss += __shfl_xor(ss, 2);
        if (q == 0) {
            float mu = s * (1.0f / K);
            float var = ss * (1.0f / K) - mu * mu;
            stats[r * 2] = mu;
            stats[r * 2 + 1] = rsqrtf(fmaxf(var, 0.f) + 1e-5f);
        }
    }
    __syncthreads();

    const int wave = t >> 6, l = t & 63;
    const int lm = l & 15, lq = l >> 4;
    const int row = row0 + wave * 16 + lm;

    float mu = 0.f, rs = 1.f;
    if (LN) {
        mu = stats[(wave * 16 + lm) * 2];
        rs = stats[(wave * 16 + lm) * 2 + 1];
    }

    f32x4 acc[NT];
#pragma unroll
    for (int i = 0; i < NT; ++i) acc[i] = (f32x4){0.f, 0.f, 0.f, 0.f};

#pragma unroll
    for (int kk = 0; kk < K / 32; ++kk) {
        f16x8 a;
        if (LN) {
            const float* xr = Xf + (long long)row * K;
            f32x4 a0 = *(const f32x4*)(xr + kk * 32 + lq * 8);
            f32x4 a1 = *(const f32x4*)(xr + kk * 32 + lq * 8 + 4);
            f32x4 w0 = *(const f32x4*)&lnwl[kk * 32 + lq * 8];
            f32x4 w1 = *(const f32x4*)&lnwl[kk * 32 + lq * 8 + 4];
            f32x4 c0 = *(const f32x4*)&lnbl[kk * 32 + lq * 8];
            f32x4 c1 = *(const f32x4*)&lnbl[kk * 32 + lq * 8 + 4];
#pragma unroll
            for (int c = 0; c < 4; ++c) {
                a[c] = (_Float16)((a0[c] - mu) * rs * w0[c] + c0[c]);
                a[4 + c] = (_Float16)((a1[c] - mu) * rs * w1[c] + c1[c]);
            }
        } else {
            a = *(const f16x8*)&Xh[(long long)row * K + kk * 32 + lq * 8];
        }

#pragma unroll
        for (int nt = 0; nt < NT; ++nt) {
            int n = nt * 16 + lm;
            int off = n * K + (((kk * 4 + lq) ^ (n & 7)) * 8);
            f16x8 bh = *(const f16x8*)&Wl[off];
            acc[nt] = __builtin_amdgcn_mfma_f32_16x16x32_f16(a, bh, acc[nt], 0, 0, 0);
        }
    }

    const int mbase = row0 + wave * 16 + lq * 4;
#pragma unroll
    for (int nt = 0; nt < NT; ++nt) {
        int c = nt * 16 + lm;
#pragma unroll
        for (int r = 0; r < 4; ++r) Y[(long long)(mbase + r) * N + c] = f2h(acc[nt][r]);
    }
}

// ---------------- CSR gather F=128 (fp16 table): 4 edge-slots/wave ----------------
__global__ __launch_bounds__(256) void agg128h(
    const u16* __restrict__ XW, const int* __restrict__ rowptr, const int* __restrict__ csrc,
    const float* __restrict__ cw, const float* __restrict__ dis, const float* __restrict__ bias,
    u16* __restrict__ OUT, int relu) {
    int node = blockIdx.x * 4 + (threadIdx.x >> 6);
    int l = threadIdx.x & 63;
    int h = l >> 4, c = l & 15;  // 4 edge slots x 16 lanes x 8 feats
    float di = dis[node];
    float acc[8] = {0.f, 0.f, 0.f, 0.f, 0.f, 0.f, 0.f, 0.f};
    if (h == 0) {
        f16x8 s = *(const f16x8*)&XW[(long long)node * 128 + c * 8];
        f32x4 b0 = *(const f32x4*)(bias + c * 8);
        f32x4 b1 = *(const f32x4*)(bias + c * 8 + 4);
        float d2 = di * di;
#pragma unroll
        for (int i = 0; i < 4; ++i) {
            acc[i] = (float)s[i] * d2 + b0[i];
            acc[4 + i] = (float)s[4 + i] * d2 + b1[i];
        }
    }
    int e1 = rowptr[node + 1];
    int e = rowptr[node] + h;
    for (; e + 4 < e1; e += 8) {
        int s0 = csrc[e], s1 = csrc[e + 4];
        float w0 = cw[e], w1 = cw[e + 4];
        f16x8 u0 = *(const f16x8*)&XW[(long long)s0 * 128 + c * 8];
        f16x8 u1 = *(const f16x8*)&XW[(long long)s1 * 128 + c * 8];
#pragma unroll
        for (int i = 0; i < 8; ++i) acc[i] += (float)u0[i] * w0 + (float)u1[i] * w1;
    }
    if (e < e1) {
        int s0 = csrc[e];
        float w0 = cw[e];
        f16x8 u0 = *(const f16x8*)&XW[(long long)s0 * 128 + c * 8];
#pragma unroll
        for (int i = 0; i < 8; ++i) acc[i] += (float)u0[i] * w0;
    }
#pragma unroll
    for (int m = 16; m <= 32; m <<= 1) {
#pragma unroll
        for (int i = 0; i < 8; ++i) acc[i] += __shfl_xor(acc[i], m);
    }
    if (h == 0) {
        f16x8 r;
#pragma unroll
        for (int i = 0; i < 8; ++i) {
            float v = relu ? fmaxf(acc[i], 0.f) : acc[i];
            r[i] = (_Float16)v;
        }
        *(f16x8*)&OUT[(long long)node * 128 + c * 8] = r;
    }
}

// ---------------- F=32 gather (fp16 table -> fp32 out): 8 edge-slots/wave ----------------
__global__ __launch_bounds__(256) void agg32h(
    const u16* __restrict__ XW, const int* __restrict__ rowptr, const int* __restrict__ csrc,
    const float* __restrict__ cw, const float* __restrict__ dis, const float* __restrict__ bias,
    float* __restrict__ OUT) {
    int node = blockIdx.x * 4 + (threadIdx.x >> 6);
    int l = threadIdx.x & 63;
    int h = l >> 3, c = l & 7;  // 8 edge slots x 8 lanes x 4 feats
    float di = dis[node];
    f32x4 acc = (f32x4){0.f, 0.f, 0.f, 0.f};
    if (h == 0) {
        f16x4 s = *(const f16x4*)&XW[(long long)node * 32 + c * 4];
        f32x4 b0 = *(const f32x4*)(bias + c * 4);
        float d2 = di * di;
#pragma unroll
        for (int i = 0; i < 4; ++i) acc[i] = (float)s[i] * d2 + b0[i];
    }
    int e1 = rowptr[node + 1];
    int e = rowptr[node] + h;
    for (; e + 8 < e1; e += 16) {
        int s0 = csrc[e], s1 = csrc[e + 8];
        float w0 = cw[e], w1 = cw[e + 8];
        f16x4 u0 = *(const f16x4*)&XW[(long long)s0 * 32 + c * 4];
        f16x4 u1 = *(const f16x4*)&XW[(long long)s1 * 32 + c * 4];
#pragma unroll
        for (int i = 0; i < 4; ++i) acc[i] += (float)u0[i] * w0 + (float)u1[i] * w1;
    }
    if (e < e1) {
        int s0 = csrc[e];
        float w0 = cw[e];
        f16x4 u0 = *(const f16x4*)&XW[(long long)s0 * 32 + c * 4];
#pragma unroll
        for (int i = 0; i < 4; ++i) acc[i] += (float)u0[i] * w0;
    }
#pragma unroll
    for (int m = 8; m <= 32; m <<= 1) {
#pragma unroll
        for (int i = 0; i < 4; ++i) acc[i] += __shfl_xor(acc[i], m);
    }
    if (h == 0) *(f32x4*)(OUT + (long long)node * 32 + c * 4) = acc;
}

extern "C" void kernel_launch(void* const* d_in, const int* in_sizes, int n_in,
                              void* d_out, int out_size, void* d_ws, size_t ws_size,
                              hipStream_t stream) {
    const float* x = (const float*)d_in[0];
    const int* ei = (const int*)d_in[1];
    const float* lnw = (const float*)d_in[2];
    const float* lnb = (const float*)d_in[3];
    const float* W1 = (const float*)d_in[4];
    const float* b1 = (const float*)d_in[5];
    const float* W2 = (const float*)d_in[6];
    const float* b2 = (const float*)d_in[7];
    const float* W3 = (const float*)d_in[8];
    const float* b3 = (const float*)d_in[9];
    float* out = (float*)d_out;

    const int n = in_sizes[0] / FIN;  // 65536
    const int E = in_sizes[1] / 2;    // 524288
    const int* src = ei;
    const int* dst = ei + E;

    char* w = (char*)d_ws;
    auto alloc = [&](size_t bytes) {
        char* p = w;
        w += (bytes + 255) & ~(size_t)255;
        return p;
    };
    int* deg = (int*)alloc((size_t)n * 4);
    int* rowp = (int*)alloc((size_t)(n + 1) * 4);
    int* cur = (int*)alloc((size_t)n * 4);
    int* part = (int*)alloc(256 * 4);
    int* poffs = (int*)alloc(256 * 4);
    float* dis = (float*)alloc((size_t)n * 4);
    int* csrc = (int*)alloc((size_t)E * 4);
    float* cwt = (float*)alloc((size_t)E * 4);
    u16* w1h = (u16*)alloc(FIN * FH * 2);
    u16* w2h = (u16*)alloc(FH * FH * 2);
    u16* w3h = (u16*)alloc(FH * FZ * 2);
    u16* bufA = (u16*)alloc((size_t)n * FH * 2);
    u16* bufB = (u16*)alloc((size_t)n * FH * 2);

    // ---- CSR build ----
    hipMemsetAsync(deg, 0, (size_t)n * 4, stream);
    deg_count<<<E / 256, 256, 0, stream>>>(dst, deg, E);
    partial_sum<<<n / 256, 256, 0, stream>>>(deg, part);
    scan_part<<<1, 256, 0, stream>>>(part, poffs);
    scan_row<<<n / 256, 256, 0, stream>>>(deg, poffs, rowp, cur, dis, n);
    csr_fill<<<E / 256, 256, 0, stream>>>(src, dst, dis, cur, csrc, cwt, E);

    // ---- weight prep (fused, fp16) ----
    w_prep_all<<<(FIN * FH + FH * FH + FH * FZ) / 256, 256, 0, stream>>>(W1, W2, W3, w1h, w2h, w3h);

    // ---- dynamic LDS opt-in ----
    const int lds1 = FIN * FH * 2 + 128 * 2 * 4 + 2 * FIN * 4;  // 68608
    const int lds2 = FH * FH * 2;                               // 32768
    const int lds3 = FZ * FH * 2;                               // 8192
    hipFuncSetAttribute((const void*)&gemm_v3<256, 128, true>,
                        hipFuncAttributeMaxDynamicSharedMemorySize, lds1);
    hipFuncSetAttribute((const void*)&gemm_v3<128, 128, false>,
                        hipFuncAttributeMaxDynamicSharedMemorySize, lds2);
    hipFuncSetAttribute((const void*)&gemm_v3<128, 32, false>,
                        hipFuncAttributeMaxDynamicSharedMemorySize, lds3);

    // ---- conv1: LN + GEMM -> gather ----
    gemm_v3<256, 128, true><<<n / 128, 512, lds1, stream>>>(x, nullptr, w1h, lnw, lnb, bufA);
    agg128h<<<n / 4, 256, 0, stream>>>(bufA, rowp, csrc, cwt, dis, b1, bufB, 1);

    // ---- conv2 ----
    gemm_v3<128, 128, false><<<n / 128, 512, lds2, stream>>>(nullptr, bufB, w2h, nullptr, nullptr, bufA);
    agg128h<<<n / 4, 256, 0, stream>>>(bufA, rowp, csrc, cwt, dis, b2, bufB, 1);

    // ---- conv3 ----
    gemm_v3<128, 32, false><<<n / 128, 512, lds3, stream>>>(nullptr, bufB, w3h, nullptr, nullptr, bufA);
    agg32h<<<n / 4, 256, 0, stream>>>(bufA, rowp, csrc, cwt, dis, b3, out);
}

// Round 6
// 196.961 us; speedup vs baseline: 1.9265x; 1.0418x over previous
//
#include <hip/hip_runtime.h>
#include <hip/hip_bf16.h>

#define FIN 256
#define FH 128
#define FZ 32

typedef unsigned short u16;
typedef unsigned int u32;
typedef __attribute__((ext_vector_type(4))) float f32x4;
typedef __attribute__((ext_vector_type(8))) _Float16 f16x8;
typedef __attribute__((ext_vector_type(4))) _Float16 f16x4;
typedef __attribute__((ext_vector_type(4))) unsigned int uint4v;

__device__ inline u16 f2h(float v) { return __builtin_bit_cast(u16, (_Float16)v); }

// ---------------- CSR build ----------------
__global__ void deg_count(const int* __restrict__ dst, int* __restrict__ deg, int E) {
    int e = blockIdx.x * 256 + threadIdx.x;
    if (e < E) atomicAdd(&deg[dst[e]], 1);
}

__global__ void partial_sum(const int* __restrict__ deg, int* __restrict__ part) {
    __shared__ int s[256];
    int t = threadIdx.x;
    s[t] = deg[blockIdx.x * 256 + t];
    __syncthreads();
    for (int o = 128; o > 0; o >>= 1) {
        if (t < o) s[t] += s[t + o];
        __syncthreads();
    }
    if (t == 0) part[blockIdx.x] = s[0];
}

__global__ void scan_part(const int* __restrict__ part, int* __restrict__ poffs) {
    __shared__ int s[256];
    int t = threadIdx.x;
    int v = part[t];
    s[t] = v;
    __syncthreads();
    for (int o = 1; o < 256; o <<= 1) {
        int add = (t >= o) ? s[t - o] : 0;
        __syncthreads();
        s[t] += add;
        __syncthreads();
    }
    poffs[t] = s[t] - v;  // exclusive
}

// row scan + rowptr + cursor + dis (fused)
__global__ void scan_row(const int* __restrict__ deg, const int* __restrict__ poffs,
                         int* __restrict__ rowptr, int* __restrict__ cur,
                         float* __restrict__ dis, int n) {
    __shared__ int s[256];
    int t = threadIdx.x;
    int i = blockIdx.x * 256 + t;
    int v = deg[i];
    s[t] = v;
    __syncthreads();
    for (int o = 1; o < 256; o <<= 1) {
        int add = (t >= o) ? s[t - o] : 0;
        __syncthreads();
        s[t] += add;
        __syncthreads();
    }
    int incl = s[t] + poffs[blockIdx.x];
    int excl = incl - v;
    rowptr[i] = excl;
    cur[i] = excl;
    dis[i] = rsqrtf((float)v + 1.0f);
    if (i == n - 1) rowptr[n] = incl;
}

// fill: only src index per slot (normalization folded into tables)
__global__ void csr_fill(const int* __restrict__ src, const int* __restrict__ dst,
                         int* __restrict__ cursor, int* __restrict__ csrc, int E) {
    int e = blockIdx.x * 256 + threadIdx.x;
    if (e >= E) return;
    int s = src[e], d = dst[e];
    int p = atomicAdd(&cursor[d], 1);
    csrc[p] = s;
}

// ---------------- weight prep (all 3): fp32 W[K][N] -> fp16 Wt[N][K] ----------------
__global__ void w_prep_all(const float* __restrict__ W1, const float* __restrict__ W2,
                           const float* __restrict__ W3, u16* __restrict__ w1h,
                           u16* __restrict__ w2h, u16* __restrict__ w3h) {
    int i = blockIdx.x * 256 + threadIdx.x;
    if (i < FIN * FH) {
        int k = i / FH, n = i % FH;
        w1h[n * FIN + k] = f2h(W1[i]);
    } else if (i < FIN * FH + FH * FH) {
        int j = i - FIN * FH;
        int k = j / FH, n = j % FH;
        w2h[n * FH + k] = f2h(W2[j]);
    } else {
        int j = i - (FIN * FH + FH * FH);
        int k = j / FZ, n = j % FZ;
        w3h[n * FH + k] = f2h(W3[j]);
    }
}

// ---------------- GEMM: fp16 MFMA, W LDS-resident (XOR-swizzled), dis-scaled fp16 output ----------------
// T[M,N](fp16) = dis[r] * ((LN? LayerNorm(Xf) : Xh)[M,K] @ W[K,N])
template <int K, int N, bool LN>
__global__ __launch_bounds__(512) void gemm_v3(
    const float* __restrict__ Xf, const u16* __restrict__ Xh, const u16* __restrict__ Wg,
    const float* __restrict__ lnw, const float* __restrict__ lnb,
    const float* __restrict__ dis, u16* __restrict__ Y) {
    constexpr int BM = 128;
    constexpr int NT = N / 16;

    extern __shared__ char smem[];
    u16* Wl = (u16*)smem;                               // [N*K] swizzled f16
    float* stats = (float*)(smem + (size_t)N * K * 2);  // [BM][2] (LN only)
    float* lnwl = stats + (LN ? BM * 2 : 0);            // [K]
    float* lnbl = lnwl + (LN ? K : 0);                  // [K]

    const int t = threadIdx.x;
    const int row0 = blockIdx.x * BM;

    // stage W once: 16B granules, swizzle k8 by n&7
    for (int i = t; i < N * K / 8; i += 512) {
        int n = i / (K / 8), k8 = i % (K / 8);
        *(uint4v*)&Wl[n * K + ((k8 ^ (n & 7)) * 8)] = *(const uint4v*)&Wg[n * K + k8 * 8];
    }

    if (LN) {
        if (t < K / 4) {
            *(f32x4*)&lnwl[t * 4] = *(const f32x4*)&lnw[t * 4];
            *(f32x4*)&lnbl[t * 4] = *(const f32x4*)&lnb[t * 4];
        }
        int r = t >> 2, q = t & 3;
        const float* xr = Xf + (long long)(row0 + r) * K + q * (K / 4);
        float s = 0.f, ss = 0.f;
#pragma unroll
        for (int j = 0; j < K / 16; ++j) {
            f32x4 f = *(const f32x4*)(xr + j * 4);
#pragma unroll
            for (int c = 0; c < 4; ++c) {
                s += f[c];
                ss += f[c] * f[c];
            }
        }
        s += __shfl_xor(s, 1);
        ss += __shfl_xor(ss, 1);
        s += __shfl_xor(s, 2);
        ss += __shfl_xor(ss, 2);
        if (q == 0) {
            float mu = s * (1.0f / K);
            float var = ss * (1.0f / K) - mu * mu;
            stats[r * 2] = mu;
            stats[r * 2 + 1] = rsqrtf(fmaxf(var, 0.f) + 1e-5f);
        }
    }
    __syncthreads();

    const int wave = t >> 6, l = t & 63;
    const int lm = l & 15, lq = l >> 4;
    const int row = row0 + wave * 16 + lm;

    float mu = 0.f, rs = 1.f;
    if (LN) {
        mu = stats[(wave * 16 + lm) * 2];
        rs = stats[(wave * 16 + lm) * 2 + 1];
    }

    f32x4 acc[NT];
#pragma unroll
    for (int i = 0; i < NT; ++i) acc[i] = (f32x4){0.f, 0.f, 0.f, 0.f};

#pragma unroll
    for (int kk = 0; kk < K / 32; ++kk) {
        f16x8 a;
        if (LN) {
            const float* xr = Xf + (long long)row * K;
            f32x4 a0 = *(const f32x4*)(xr + kk * 32 + lq * 8);
            f32x4 a1 = *(const f32x4*)(xr + kk * 32 + lq * 8 + 4);
            f32x4 w0 = *(const f32x4*)&lnwl[kk * 32 + lq * 8];
            f32x4 w1 = *(const f32x4*)&lnwl[kk * 32 + lq * 8 + 4];
            f32x4 c0 = *(const f32x4*)&lnbl[kk * 32 + lq * 8];
            f32x4 c1 = *(const f32x4*)&lnbl[kk * 32 + lq * 8 + 4];
#pragma unroll
            for (int c = 0; c < 4; ++c) {
                a[c] = (_Float16)((a0[c] - mu) * rs * w0[c] + c0[c]);
                a[4 + c] = (_Float16)((a1[c] - mu) * rs * w1[c] + c1[c]);
            }
        } else {
            a = *(const f16x8*)&Xh[(long long)row * K + kk * 32 + lq * 8];
        }

#pragma unroll
        for (int nt = 0; nt < NT; ++nt) {
            int n = nt * 16 + lm;
            int off = n * K + (((kk * 4 + lq) ^ (n & 7)) * 8);
            f16x8 bh = *(const f16x8*)&Wl[off];
            acc[nt] = __builtin_amdgcn_mfma_f32_16x16x32_f16(a, bh, acc[nt], 0, 0, 0);
        }
    }

    const int mbase = row0 + wave * 16 + lq * 4;
    f32x4 d4 = *(const f32x4*)(dis + mbase);
#pragma unroll
    for (int nt = 0; nt < NT; ++nt) {
        int c = nt * 16 + lm;
#pragma unroll
        for (int r = 0; r < 4; ++r) Y[(long long)(mbase + r) * N + c] = f2h(acc[nt][r] * d4[r]);
    }
}

// ---------------- CSR gather F=128: out = relu(dis_d*(sum T_s + T_d) + b) ----------------
__global__ __launch_bounds__(256) void agg128h(
    const u16* __restrict__ T, const int* __restrict__ rowptr, const int* __restrict__ csrc,
    const float* __restrict__ dis, const float* __restrict__ bias,
    u16* __restrict__ OUT, int relu) {
    int node = blockIdx.x * 4 + (threadIdx.x >> 6);
    int l = threadIdx.x & 63;
    int h = l >> 4, c = l & 15;  // 4 edge slots x 16 lanes x 8 feats
    float di = dis[node];
    float acc[8] = {0.f, 0.f, 0.f, 0.f, 0.f, 0.f, 0.f, 0.f};
    if (h == 0) {
        f16x8 s = *(const f16x8*)&T[(long long)node * 128 + c * 8];
#pragma unroll
        for (int i = 0; i < 8; ++i) acc[i] = (float)s[i];
    }
    int e1 = rowptr[node + 1];
    int e = rowptr[node] + h;
    for (; e + 4 < e1; e += 8) {
        int s0 = csrc[e], s1 = csrc[e + 4];
        f16x8 u0 = *(const f16x8*)&T[(long long)s0 * 128 + c * 8];
        f16x8 u1 = *(const f16x8*)&T[(long long)s1 * 128 + c * 8];
#pragma unroll
        for (int i = 0; i < 8; ++i) acc[i] += (float)u0[i] + (float)u1[i];
    }
    if (e < e1) {
        int s0 = csrc[e];
        f16x8 u0 = *(const f16x8*)&T[(long long)s0 * 128 + c * 8];
#pragma unroll
        for (int i = 0; i < 8; ++i) acc[i] += (float)u0[i];
    }
#pragma unroll
    for (int m = 16; m <= 32; m <<= 1) {
#pragma unroll
        for (int i = 0; i < 8; ++i) acc[i] += __shfl_xor(acc[i], m);
    }
    if (h == 0) {
        f32x4 b0 = *(const f32x4*)(bias + c * 8);
        f32x4 b1 = *(const f32x4*)(bias + c * 8 + 4);
        f16x8 r;
#pragma unroll
        for (int i = 0; i < 8; ++i) {
            float b = (i < 4) ? b0[i] : b1[i - 4];
            float v = acc[i] * di + b;
            if (relu) v = fmaxf(v, 0.f);
            r[i] = (_Float16)v;
        }
        *(f16x8*)&OUT[(long long)node * 128 + c * 8] = r;
    }
}

// ---------------- F=32 gather -> fp32 out ----------------
__global__ __launch_bounds__(256) void agg32h(
    const u16* __restrict__ T, const int* __restrict__ rowptr, const int* __restrict__ csrc,
    const float* __restrict__ dis, const float* __restrict__ bias,
    float* __restrict__ OUT) {
    int node = blockIdx.x * 4 + (threadIdx.x >> 6);
    int l = threadIdx.x & 63;
    int h = l >> 3, c = l & 7;  // 8 edge slots x 8 lanes x 4 feats
    float di = dis[node];
    f32x4 acc = (f32x4){0.f, 0.f, 0.f, 0.f};
    if (h == 0) {
        f16x4 s = *(const f16x4*)&T[(long long)node * 32 + c * 4];
#pragma unroll
        for (int i = 0; i < 4; ++i) acc[i] = (float)s[i];
    }
    int e1 = rowptr[node + 1];
    int e = rowptr[node] + h;
    for (; e + 8 < e1; e += 16) {
        int s0 = csrc[e], s1 = csrc[e + 8];
        f16x4 u0 = *(const f16x4*)&T[(long long)s0 * 32 + c * 4];
        f16x4 u1 = *(const f16x4*)&T[(long long)s1 * 32 + c * 4];
#pragma unroll
        for (int i = 0; i < 4; ++i) acc[i] += (float)u0[i] + (float)u1[i];
    }
    if (e < e1) {
        int s0 = csrc[e];
        f16x4 u0 = *(const f16x4*)&T[(long long)s0 * 32 + c * 4];
#pragma unroll
        for (int i = 0; i < 4; ++i) acc[i] += (float)u0[i];
    }
#pragma unroll
    for (int m = 8; m <= 32; m <<= 1) {
#pragma unroll
        for (int i = 0; i < 4; ++i) acc[i] += __shfl_xor(acc[i], m);
    }
    if (h == 0) {
        f32x4 b0 = *(const f32x4*)(bias + c * 4);
        f32x4 r;
#pragma unroll
        for (int i = 0; i < 4; ++i) r[i] = acc[i] * di + b0[i];
        *(f32x4*)(OUT + (long long)node * 32 + c * 4) = r;
    }
}

extern "C" void kernel_launch(void* const* d_in, const int* in_sizes, int n_in,
                              void* d_out, int out_size, void* d_ws, size_t ws_size,
                              hipStream_t stream) {
    const float* x = (const float*)d_in[0];
    const int* ei = (const int*)d_in[1];
    const float* lnw = (const float*)d_in[2];
    const float* lnb = (const float*)d_in[3];
    const float* W1 = (const float*)d_in[4];
    const float* b1 = (const float*)d_in[5];
    const float* W2 = (const float*)d_in[6];
    const float* b2 = (const float*)d_in[7];
    const float* W3 = (const float*)d_in[8];
    const float* b3 = (const float*)d_in[9];
    float* out = (float*)d_out;

    const int n = in_sizes[0] / FIN;  // 65536
    const int E = in_sizes[1] / 2;    // 524288
    const int* src = ei;
    const int* dst = ei + E;

    char* w = (char*)d_ws;
    auto alloc = [&](size_t bytes) {
        char* p = w;
        w += (bytes + 255) & ~(size_t)255;
        return p;
    };
    int* deg = (int*)alloc((size_t)n * 4);
    int* rowp = (int*)alloc((size_t)(n + 1) * 4);
    int* cur = (int*)alloc((size_t)n * 4);
    int* part = (int*)alloc(256 * 4);
    int* poffs = (int*)alloc(256 * 4);
    float* dis = (float*)alloc((size_t)n * 4);
    int* csrc = (int*)alloc((size_t)E * 4);
    u16* w1h = (u16*)alloc(FIN * FH * 2);
    u16* w2h = (u16*)alloc(FH * FH * 2);
    u16* w3h = (u16*)alloc(FH * FZ * 2);
    u16* bufA = (u16*)alloc((size_t)n * FH * 2);
    u16* bufB = (u16*)alloc((size_t)n * FH * 2);

    // ---- CSR build ----
    hipMemsetAsync(deg, 0, (size_t)n * 4, stream);
    deg_count<<<E / 256, 256, 0, stream>>>(dst, deg, E);
    partial_sum<<<n / 256, 256, 0, stream>>>(deg, part);
    scan_part<<<1, 256, 0, stream>>>(part, poffs);
    scan_row<<<n / 256, 256, 0, stream>>>(deg, poffs, rowp, cur, dis, n);
    csr_fill<<<E / 256, 256, 0, stream>>>(src, dst, cur, csrc, E);

    // ---- weight prep (fused, fp16) ----
    w_prep_all<<<(FIN * FH + FH * FH + FH * FZ) / 256, 256, 0, stream>>>(W1, W2, W3, w1h, w2h, w3h);

    // ---- dynamic LDS opt-in ----
    const int lds1 = FIN * FH * 2 + 128 * 2 * 4 + 2 * FIN * 4;  // 68608
    const int lds2 = FH * FH * 2;                               // 32768
    const int lds3 = FZ * FH * 2;                               // 8192
    hipFuncSetAttribute((const void*)&gemm_v3<256, 128, true>,
                        hipFuncAttributeMaxDynamicSharedMemorySize, lds1);
    hipFuncSetAttribute((const void*)&gemm_v3<128, 128, false>,
                        hipFuncAttributeMaxDynamicSharedMemorySize, lds2);
    hipFuncSetAttribute((const void*)&gemm_v3<128, 32, false>,
                        hipFuncAttributeMaxDynamicSharedMemorySize, lds3);

    // ---- conv1: LN + GEMM(scaled) -> gather ----
    gemm_v3<256, 128, true><<<n / 128, 512, lds1, stream>>>(x, nullptr, w1h, lnw, lnb, dis, bufA);
    agg128h<<<n / 4, 256, 0, stream>>>(bufA, rowp, csrc, dis, b1, bufB, 1);

    // ---- conv2 ----
    gemm_v3<128, 128, false><<<n / 128, 512, lds2, stream>>>(nullptr, bufB, w2h, nullptr, nullptr, dis, bufA);
    agg128h<<<n / 4, 256, 0, stream>>>(bufA, rowp, csrc, dis, b2, bufB, 1);

    // ---- conv3 ----
    gemm_v3<128, 32, false><<<n / 128, 512, lds3, stream>>>(nullptr, bufB, w3h, nullptr, nullptr, dis, bufA);
    agg32h<<<n / 4, 256, 0, stream>>>(bufA, rowp, csrc, dis, b3, out);
}

// Round 7
// 191.529 us; speedup vs baseline: 1.9811x; 1.0284x over previous
//
#include <hip/hip_runtime.h>
#include <hip/hip_bf16.h>

#define FIN 256
#define FH 128
#define FZ 32

typedef unsigned short u16;
typedef unsigned int u32;
typedef __attribute__((ext_vector_type(4))) float f32x4;
typedef __attribute__((ext_vector_type(8))) _Float16 f16x8;
typedef __attribute__((ext_vector_type(4))) _Float16 f16x4;
typedef __attribute__((ext_vector_type(4))) unsigned int uint4v;

__device__ inline u16 f2h(float v) { return __builtin_bit_cast(u16, (_Float16)v); }

// ---------------- prep: zero deg/total + weight transpose/convert (one kernel) ----------------
// blocks [0,256): zero deg (and total); blocks [256,464): w_prep
__global__ __launch_bounds__(256) void prep(const float* __restrict__ W1,
                                            const float* __restrict__ W2,
                                            const float* __restrict__ W3,
                                            u16* __restrict__ w1h, u16* __restrict__ w2h,
                                            u16* __restrict__ w3h, int* __restrict__ deg,
                                            int* __restrict__ total) {
    int b = blockIdx.x, t = threadIdx.x;
    if (b < 256) {
        deg[b * 256 + t] = 0;
        if (b == 0 && t == 0) *total = 0;
        return;
    }
    int i = (b - 256) * 256 + t;
    if (i < FIN * FH) {
        int k = i / FH, n = i % FH;
        w1h[n * FIN + k] = f2h(W1[i]);
    } else if (i < FIN * FH + FH * FH) {
        int j = i - FIN * FH;
        int k = j / FH, n = j % FH;
        w2h[n * FH + k] = f2h(W2[j]);
    } else {
        int j = i - (FIN * FH + FH * FH);
        int k = j / FZ, n = j % FZ;
        w3h[n * FH + k] = f2h(W3[j]);
    }
}

// ---------------- degree count ----------------
__global__ void deg_count(const int* __restrict__ dst, int* __restrict__ deg, int E) {
    int e = blockIdx.x * 256 + threadIdx.x;
    if (e < E) atomicAdd(&deg[dst[e]], 1);
}

// ---------------- single-kernel scan: block-local scan + atomic base ----------------
// Row order across blocks is arbitrary (valid disjoint partition of [0,E)).
__global__ __launch_bounds__(256) void scan_fused(const int* __restrict__ deg,
                                                  int* __restrict__ total,
                                                  int* __restrict__ rowstart,
                                                  int* __restrict__ cur,
                                                  float* __restrict__ dis) {
    __shared__ int s[256];
    __shared__ int base;
    int t = threadIdx.x;
    int i = blockIdx.x * 256 + t;
    int v = deg[i];
    s[t] = v;
    __syncthreads();
    for (int o = 1; o < 256; o <<= 1) {
        int add = (t >= o) ? s[t - o] : 0;
        __syncthreads();
        s[t] += add;
        __syncthreads();
    }
    if (t == 255) base = atomicAdd(total, s[255]);
    __syncthreads();
    int excl = s[t] - v + base;
    rowstart[i] = excl;
    cur[i] = excl;
    dis[i] = rsqrtf((float)v + 1.0f);
}

// ---------------- GEMM (optionally fused with csr_fill): fp16 MFMA, W LDS-resident ----------------
// T[M,N](fp16) = dis[r] * ((LN? LayerNorm(Xf) : Xh)[M,K] @ W[K,N])
// FILL: blocks with blockIdx%3!=0 instead scatter 512 edges each into csrc.
template <int K, int N, bool LN, bool FILL>
__global__ __launch_bounds__(512) void gemm_v4(
    const float* __restrict__ Xf, const u16* __restrict__ Xh, const u16* __restrict__ Wg,
    const float* __restrict__ lnw, const float* __restrict__ lnb,
    const float* __restrict__ dis, u16* __restrict__ Y,
    const int* __restrict__ src, const int* __restrict__ dst,
    int* __restrict__ cursor, int* __restrict__ csrc, int E) {
    constexpr int BM = 128;
    constexpr int NT = N / 16;

    int gb;
    if (FILL) {
        int m3 = blockIdx.x % 3;
        if (m3 != 0) {
            int fid = (blockIdx.x / 3) * 2 + m3 - 1;
            int e = fid * 512 + threadIdx.x;
            if (e < E) {
                int s = src[e], d = dst[e];
                int p = atomicAdd(&cursor[d], 1);
                csrc[p] = s;
            }
            return;
        }
        gb = blockIdx.x / 3;
    } else {
        gb = blockIdx.x;
    }

    extern __shared__ char smem[];
    u16* Wl = (u16*)smem;                               // [N*K] swizzled f16
    float* stats = (float*)(smem + (size_t)N * K * 2);  // [BM][2] (LN only)
    float* lnwl = stats + (LN ? BM * 2 : 0);            // [K]
    float* lnbl = lnwl + (LN ? K : 0);                  // [K]

    const int t = threadIdx.x;
    const int row0 = gb * BM;

    // stage W once: 16B granules, swizzle k8 by n&7
    for (int i = t; i < N * K / 8; i += 512) {
        int n = i / (K / 8), k8 = i % (K / 8);
        *(uint4v*)&Wl[n * K + ((k8 ^ (n & 7)) * 8)] = *(const uint4v*)&Wg[n * K + k8 * 8];
    }

    if (LN) {
        if (t < K / 4) {
            *(f32x4*)&lnwl[t * 4] = *(const f32x4*)&lnw[t * 4];
            *(f32x4*)&lnbl[t * 4] = *(const f32x4*)&lnb[t * 4];
        }
        int r = t >> 2, q = t & 3;
        const float* xr = Xf + (long long)(row0 + r) * K + q * (K / 4);
        float s = 0.f, ss = 0.f;
#pragma unroll
        for (int j = 0; j < K / 16; ++j) {
            f32x4 f = *(const f32x4*)(xr + j * 4);
#pragma unroll
            for (int c = 0; c < 4; ++c) {
                s += f[c];
                ss += f[c] * f[c];
            }
        }
        s += __shfl_xor(s, 1);
        ss += __shfl_xor(ss, 1);
        s += __shfl_xor(s, 2);
        ss += __shfl_xor(ss, 2);
        if (q == 0) {
            float mu = s * (1.0f / K);
            float var = ss * (1.0f / K) - mu * mu;
            stats[r * 2] = mu;
            stats[r * 2 + 1] = rsqrtf(fmaxf(var, 0.f) + 1e-5f);
        }
    }
    __syncthreads();

    const int wave = t >> 6, l = t & 63;
    const int lm = l & 15, lq = l >> 4;
    const int row = row0 + wave * 16 + lm;

    float mu = 0.f, rs = 1.f;
    if (LN) {
        mu = stats[(wave * 16 + lm) * 2];
        rs = stats[(wave * 16 + lm) * 2 + 1];
    }

    f32x4 acc[NT];
#pragma unroll
    for (int i = 0; i < NT; ++i) acc[i] = (f32x4){0.f, 0.f, 0.f, 0.f};

#pragma unroll
    for (int kk = 0; kk < K / 32; ++kk) {
        f16x8 a;
        if (LN) {
            const float* xr = Xf + (long long)row * K;
            f32x4 a0 = *(const f32x4*)(xr + kk * 32 + lq * 8);
            f32x4 a1 = *(const f32x4*)(xr + kk * 32 + lq * 8 + 4);
            f32x4 w0 = *(const f32x4*)&lnwl[kk * 32 + lq * 8];
            f32x4 w1 = *(const f32x4*)&lnwl[kk * 32 + lq * 8 + 4];
            f32x4 c0 = *(const f32x4*)&lnbl[kk * 32 + lq * 8];
            f32x4 c1 = *(const f32x4*)&lnbl[kk * 32 + lq * 8 + 4];
#pragma unroll
            for (int c = 0; c < 4; ++c) {
                a[c] = (_Float16)((a0[c] - mu) * rs * w0[c] + c0[c]);
                a[4 + c] = (_Float16)((a1[c] - mu) * rs * w1[c] + c1[c]);
            }
        } else {
            a = *(const f16x8*)&Xh[(long long)row * K + kk * 32 + lq * 8];
        }

#pragma unroll
        for (int nt = 0; nt < NT; ++nt) {
            int n = nt * 16 + lm;
            int off = n * K + (((kk * 4 + lq) ^ (n & 7)) * 8);
            f16x8 bh = *(const f16x8*)&Wl[off];
            acc[nt] = __builtin_amdgcn_mfma_f32_16x16x32_f16(a, bh, acc[nt], 0, 0, 0);
        }
    }

    const int mbase = row0 + wave * 16 + lq * 4;
    f32x4 d4 = *(const f32x4*)(dis + mbase);
#pragma unroll
    for (int nt = 0; nt < NT; ++nt) {
        int c = nt * 16 + lm;
#pragma unroll
        for (int r = 0; r < 4; ++r) Y[(long long)(mbase + r) * N + c] = f2h(acc[nt][r] * d4[r]);
    }
}

// ---------------- CSR gather F=128: out = relu(dis_d*(sum T_s + T_d) + b) ----------------
__global__ __launch_bounds__(256) void agg128h(
    const u16* __restrict__ T, const int* __restrict__ rowstart, const int* __restrict__ degv,
    const int* __restrict__ csrc, const float* __restrict__ dis, const float* __restrict__ bias,
    u16* __restrict__ OUT, int relu) {
    int node = blockIdx.x * 4 + (threadIdx.x >> 6);
    int l = threadIdx.x & 63;
    int h = l >> 4, c = l & 15;  // 4 edge slots x 16 lanes x 8 feats
    float di = dis[node];
    float acc[8] = {0.f, 0.f, 0.f, 0.f, 0.f, 0.f, 0.f, 0.f};
    if (h == 0) {
        f16x8 s = *(const f16x8*)&T[(long long)node * 128 + c * 8];
#pragma unroll
        for (int i = 0; i < 8; ++i) acc[i] = (float)s[i];
    }
    int e0 = rowstart[node];
    int e1 = e0 + degv[node];
    int e = e0 + h;
    for (; e + 4 < e1; e += 8) {
        int s0 = csrc[e], s1 = csrc[e + 4];
        f16x8 u0 = *(const f16x8*)&T[(long long)s0 * 128 + c * 8];
        f16x8 u1 = *(const f16x8*)&T[(long long)s1 * 128 + c * 8];
#pragma unroll
        for (int i = 0; i < 8; ++i) acc[i] += (float)u0[i] + (float)u1[i];
    }
    if (e < e1) {
        int s0 = csrc[e];
        f16x8 u0 = *(const f16x8*)&T[(long long)s0 * 128 + c * 8];
#pragma unroll
        for (int i = 0; i < 8; ++i) acc[i] += (float)u0[i];
    }
#pragma unroll
    for (int m = 16; m <= 32; m <<= 1) {
#pragma unroll
        for (int i = 0; i < 8; ++i) acc[i] += __shfl_xor(acc[i], m);
    }
    if (h == 0) {
        f32x4 b0 = *(const f32x4*)(bias + c * 8);
        f32x4 b1 = *(const f32x4*)(bias + c * 8 + 4);
        f16x8 r;
#pragma unroll
        for (int i = 0; i < 8; ++i) {
            float b = (i < 4) ? b0[i] : b1[i - 4];
            float v = acc[i] * di + b;
            if (relu) v = fmaxf(v, 0.f);
            r[i] = (_Float16)v;
        }
        *(f16x8*)&OUT[(long long)node * 128 + c * 8] = r;
    }
}

// ---------------- F=32 gather -> fp32 out ----------------
__global__ __launch_bounds__(256) void agg32h(
    const u16* __restrict__ T, const int* __restrict__ rowstart, const int* __restrict__ degv,
    const int* __restrict__ csrc, const float* __restrict__ dis, const float* __restrict__ bias,
    float* __restrict__ OUT) {
    int node = blockIdx.x * 4 + (threadIdx.x >> 6);
    int l = threadIdx.x & 63;
    int h = l >> 3, c = l & 7;  // 8 edge slots x 8 lanes x 4 feats
    float di = dis[node];
    f32x4 acc = (f32x4){0.f, 0.f, 0.f, 0.f};
    if (h == 0) {
        f16x4 s = *(const f16x4*)&T[(long long)node * 32 + c * 4];
#pragma unroll
        for (int i = 0; i < 4; ++i) acc[i] = (float)s[i];
    }
    int e0 = rowstart[node];
    int e1 = e0 + degv[node];
    int e = e0 + h;
    for (; e + 8 < e1; e += 16) {
        int s0 = csrc[e], s1 = csrc[e + 8];
        f16x4 u0 = *(const f16x4*)&T[(long long)s0 * 32 + c * 4];
        f16x4 u1 = *(const f16x4*)&T[(long long)s1 * 32 + c * 4];
#pragma unroll
        for (int i = 0; i < 4; ++i) acc[i] += (float)u0[i] + (float)u1[i];
    }
    if (e < e1) {
        int s0 = csrc[e];
        f16x4 u0 = *(const f16x4*)&T[(long long)s0 * 32 + c * 4];
#pragma unroll
        for (int i = 0; i < 4; ++i) acc[i] += (float)u0[i];
    }
#pragma unroll
    for (int m = 8; m <= 32; m <<= 1) {
#pragma unroll
        for (int i = 0; i < 4; ++i) acc[i] += __shfl_xor(acc[i], m);
    }
    if (h == 0) {
        f32x4 b0 = *(const f32x4*)(bias + c * 4);
        f32x4 r;
#pragma unroll
        for (int i = 0; i < 4; ++i) r[i] = acc[i] * di + b0[i];
        *(f32x4*)(OUT + (long long)node * 32 + c * 4) = r;
    }
}

extern "C" void kernel_launch(void* const* d_in, const int* in_sizes, int n_in,
                              void* d_out, int out_size, void* d_ws, size_t ws_size,
                              hipStream_t stream) {
    const float* x = (const float*)d_in[0];
    const int* ei = (const int*)d_in[1];
    const float* lnw = (const float*)d_in[2];
    const float* lnb = (const float*)d_in[3];
    const float* W1 = (const float*)d_in[4];
    const float* b1 = (const float*)d_in[5];
    const float* W2 = (const float*)d_in[6];
    const float* b2 = (const float*)d_in[7];
    const float* W3 = (const float*)d_in[8];
    const float* b3 = (const float*)d_in[9];
    float* out = (float*)d_out;

    const int n = in_sizes[0] / FIN;  // 65536
    const int E = in_sizes[1] / 2;    // 524288
    const int* src = ei;
    const int* dst = ei + E;

    char* w = (char*)d_ws;
    auto alloc = [&](size_t bytes) {
        char* p = w;
        w += (bytes + 255) & ~(size_t)255;
        return p;
    };
    int* deg = (int*)alloc((size_t)n * 4);
    int* rowstart = (int*)alloc((size_t)n * 4);
    int* cur = (int*)alloc((size_t)n * 4);
    int* total = (int*)alloc(256);
    float* dis = (float*)alloc((size_t)n * 4);
    int* csrc = (int*)alloc((size_t)E * 4);
    u16* w1h = (u16*)alloc(FIN * FH * 2);
    u16* w2h = (u16*)alloc(FH * FH * 2);
    u16* w3h = (u16*)alloc(FH * FZ * 2);
    u16* bufA = (u16*)alloc((size_t)n * FH * 2);
    u16* bufB = (u16*)alloc((size_t)n * FH * 2);

    // ---- dynamic LDS opt-in ----
    const int lds1 = FIN * FH * 2 + 128 * 2 * 4 + 2 * FIN * 4;  // 68608
    const int lds2 = FH * FH * 2;                               // 32768
    const int lds3 = FZ * FH * 2;                               // 8192
    hipFuncSetAttribute((const void*)&gemm_v4<256, 128, true, true>,
                        hipFuncAttributeMaxDynamicSharedMemorySize, lds1);
    hipFuncSetAttribute((const void*)&gemm_v4<128, 128, false, false>,
                        hipFuncAttributeMaxDynamicSharedMemorySize, lds2);
    hipFuncSetAttribute((const void*)&gemm_v4<128, 32, false, false>,
                        hipFuncAttributeMaxDynamicSharedMemorySize, lds3);

    // 1) prep: zero deg/total + weight convert
    prep<<<464, 256, 0, stream>>>(W1, W2, W3, w1h, w2h, w3h, deg, total);
    // 2) degree histogram
    deg_count<<<E / 256, 256, 0, stream>>>(dst, deg, E);
    // 3) single-kernel scan (atomic block bases) + dis + cursor
    scan_fused<<<n / 256, 256, 0, stream>>>(deg, total, rowstart, cur, dis);
    // 4) conv1 GEMM (LN + dis-fold) fused with csr_fill: 512 gemm blocks + 1024 fill blocks
    gemm_v4<256, 128, true, true><<<(n / 128) * 3, 512, lds1, stream>>>(
        x, nullptr, w1h, lnw, lnb, dis, bufA, src, dst, cur, csrc, E);
    // 5) conv1 aggregate
    agg128h<<<n / 4, 256, 0, stream>>>(bufA, rowstart, deg, csrc, dis, b1, bufB, 1);
    // 6) conv2 GEMM
    gemm_v4<128, 128, false, false><<<n / 128, 512, lds2, stream>>>(
        nullptr, bufB, w2h, nullptr, nullptr, dis, bufA, nullptr, nullptr, nullptr, nullptr, 0);
    // 7) conv2 aggregate
    agg128h<<<n / 4, 256, 0, stream>>>(bufA, rowstart, deg, csrc, dis, b2, bufB, 1);
    // 8) conv3 GEMM
    gemm_v4<128, 32, false, false><<<n / 128, 512, lds3, stream>>>(
        nullptr, bufB, w3h, nullptr, nullptr, dis, bufA, nullptr, nullptr, nullptr, nullptr, 0);
    // 9) conv3 aggregate -> out
    agg32h<<<n / 4, 256, 0, stream>>>(bufA, rowstart, deg, csrc, dis, b3, out);
}

// Round 8
// 176.264 us; speedup vs baseline: 2.1527x; 1.0866x over previous
//
#include <hip/hip_runtime.h>
#include <hip/hip_bf16.h>

#define FIN 256
#define FH 128
#define FZ 32

typedef unsigned short u16;
typedef unsigned int u32;
typedef __attribute__((ext_vector_type(4))) float f32x4;
typedef __attribute__((ext_vector_type(8))) _Float16 f16x8;
typedef __attribute__((ext_vector_type(4))) _Float16 f16x4;
typedef __attribute__((ext_vector_type(4))) unsigned int uint4v;

__device__ inline u16 f2h(float v) { return __builtin_bit_cast(u16, (_Float16)v); }

// ---------------- prep: zero deg/total + weight transpose/convert (one kernel) ----------------
__global__ __launch_bounds__(256) void prep(const float* __restrict__ W1,
                                            const float* __restrict__ W2,
                                            const float* __restrict__ W3,
                                            u16* __restrict__ w1h, u16* __restrict__ w2h,
                                            u16* __restrict__ w3h, int* __restrict__ deg,
                                            int* __restrict__ total) {
    int b = blockIdx.x, t = threadIdx.x;
    if (b < 256) {
        deg[b * 256 + t] = 0;
        if (b == 0 && t == 0) *total = 0;
        return;
    }
    int i = (b - 256) * 256 + t;
    if (i < FIN * FH) {
        int k = i / FH, n = i % FH;
        w1h[n * FIN + k] = f2h(W1[i]);
    } else if (i < FIN * FH + FH * FH) {
        int j = i - FIN * FH;
        int k = j / FH, n = j % FH;
        w2h[n * FH + k] = f2h(W2[j]);
    } else {
        int j = i - (FIN * FH + FH * FH);
        int k = j / FZ, n = j % FZ;
        w3h[n * FH + k] = f2h(W3[j]);
    }
}

// ---------------- degree count + per-edge rank (atomic return value) ----------------
__global__ void deg_count(const int* __restrict__ dst, int* __restrict__ deg,
                          int* __restrict__ erank, int E) {
    int e = blockIdx.x * 256 + threadIdx.x;
    if (e < E) erank[e] = atomicAdd(&deg[dst[e]], 1);
}

// ---------------- single-kernel scan: block-local scan + atomic base ----------------
__global__ __launch_bounds__(256) void scan_fused(const int* __restrict__ deg,
                                                  int* __restrict__ total,
                                                  int* __restrict__ rowstart,
                                                  float* __restrict__ dis) {
    __shared__ int s[256];
    __shared__ int base;
    int t = threadIdx.x;
    int i = blockIdx.x * 256 + t;
    int v = deg[i];
    s[t] = v;
    __syncthreads();
    for (int o = 1; o < 256; o <<= 1) {
        int add = (t >= o) ? s[t - o] : 0;
        __syncthreads();
        s[t] += add;
        __syncthreads();
    }
    if (t == 255) base = atomicAdd(total, s[255]);
    __syncthreads();
    rowstart[i] = s[t] - v + base;
    dis[i] = rsqrtf((float)v + 1.0f);
}

// ---------------- GEMM: fp16 MFMA, W LDS-resident; optional head-fused no-atomic csr fill ----------------
// T[M,N](fp16) = dis[r] * ((LN? LayerNorm(Xf) : Xh)[M,K] @ W[K,N])
template <int K, int N, bool LN, bool FILL>
__global__ __launch_bounds__(512) void gemm_v5(
    const float* __restrict__ Xf, const u16* __restrict__ Xh, const u16* __restrict__ Wg,
    const float* __restrict__ lnw, const float* __restrict__ lnb,
    const float* __restrict__ dis, u16* __restrict__ Y,
    const int* __restrict__ src, const int* __restrict__ dst,
    const int* __restrict__ erank, const int* __restrict__ rowstart,
    int* __restrict__ csrc, int E) {
    constexpr int BM = 128;
    constexpr int NT = N / 16;

    extern __shared__ char smem[];
    u16* Wl = (u16*)smem;                               // [N*K] swizzled f16
    float* stats = (float*)(smem + (size_t)N * K * 2);  // [BM][2] (LN only)
    float* lnwl = stats + (LN ? BM * 2 : 0);            // [K]
    float* lnbl = lnwl + (LN ? K : 0);                  // [K]

    const int t = threadIdx.x;
    const int row0 = blockIdx.x * BM;

    if (FILL) {
        // scatter this block's edge chunk (no atomics; stores fly under the gemm work)
        int epb = E / gridDim.x;  // 1024
        int base = blockIdx.x * epb;
#pragma unroll
        for (int j = 0; j < 2; ++j) {
            int e = base + j * 512 + t;
            int d = dst[e];
            csrc[rowstart[d] + erank[e]] = src[e];
        }
    }

    // stage W once: 16B granules, swizzle k8 by n&7
    for (int i = t; i < N * K / 8; i += 512) {
        int n = i / (K / 8), k8 = i % (K / 8);
        *(uint4v*)&Wl[n * K + ((k8 ^ (n & 7)) * 8)] = *(const uint4v*)&Wg[n * K + k8 * 8];
    }

    if (LN) {
        if (t < K / 4) {
            *(f32x4*)&lnwl[t * 4] = *(const f32x4*)&lnw[t * 4];
            *(f32x4*)&lnbl[t * 4] = *(const f32x4*)&lnb[t * 4];
        }
        int r = t >> 2, q = t & 3;
        const float* xr = Xf + (long long)(row0 + r) * K + q * (K / 4);
        float s = 0.f, ss = 0.f;
#pragma unroll
        for (int j = 0; j < K / 16; ++j) {
            f32x4 f = *(const f32x4*)(xr + j * 4);
#pragma unroll
            for (int c = 0; c < 4; ++c) {
                s += f[c];
                ss += f[c] * f[c];
            }
        }
        s += __shfl_xor(s, 1);
        ss += __shfl_xor(ss, 1);
        s += __shfl_xor(s, 2);
        ss += __shfl_xor(ss, 2);
        if (q == 0) {
            float mu = s * (1.0f / K);
            float var = ss * (1.0f / K) - mu * mu;
            stats[r * 2] = mu;
            stats[r * 2 + 1] = rsqrtf(fmaxf(var, 0.f) + 1e-5f);
        }
    }
    __syncthreads();

    const int wave = t >> 6, l = t & 63;
    const int lm = l & 15, lq = l >> 4;
    const int row = row0 + wave * 16 + lm;

    float mu = 0.f, rs = 1.f;
    if (LN) {
        mu = stats[(wave * 16 + lm) * 2];
        rs = stats[(wave * 16 + lm) * 2 + 1];
    }

    f32x4 acc[NT];
#pragma unroll
    for (int i = 0; i < NT; ++i) acc[i] = (f32x4){0.f, 0.f, 0.f, 0.f};

#pragma unroll
    for (int kk = 0; kk < K / 32; ++kk) {
        f16x8 a;
        if (LN) {
            const float* xr = Xf + (long long)row * K;
            f32x4 a0 = *(const f32x4*)(xr + kk * 32 + lq * 8);
            f32x4 a1 = *(const f32x4*)(xr + kk * 32 + lq * 8 + 4);
            f32x4 w0 = *(const f32x4*)&lnwl[kk * 32 + lq * 8];
            f32x4 w1 = *(const f32x4*)&lnwl[kk * 32 + lq * 8 + 4];
            f32x4 c0 = *(const f32x4*)&lnbl[kk * 32 + lq * 8];
            f32x4 c1 = *(const f32x4*)&lnbl[kk * 32 + lq * 8 + 4];
#pragma unroll
            for (int c = 0; c < 4; ++c) {
                a[c] = (_Float16)((a0[c] - mu) * rs * w0[c] + c0[c]);
                a[4 + c] = (_Float16)((a1[c] - mu) * rs * w1[c] + c1[c]);
            }
        } else {
            a = *(const f16x8*)&Xh[(long long)row * K + kk * 32 + lq * 8];
        }

#pragma unroll
        for (int nt = 0; nt < NT; ++nt) {
            int n = nt * 16 + lm;
            int off = n * K + (((kk * 4 + lq) ^ (n & 7)) * 8);
            f16x8 bh = *(const f16x8*)&Wl[off];
            acc[nt] = __builtin_amdgcn_mfma_f32_16x16x32_f16(a, bh, acc[nt], 0, 0, 0);
        }
    }

    const int mbase = row0 + wave * 16 + lq * 4;
    f32x4 d4 = *(const f32x4*)(dis + mbase);
#pragma unroll
    for (int nt = 0; nt < NT; ++nt) {
        int c = nt * 16 + lm;
#pragma unroll
        for (int r = 0; r < 4; ++r) Y[(long long)(mbase + r) * N + c] = f2h(acc[nt][r] * d4[r]);
    }
}

// ---------------- CSR gather F=128: out = relu(dis_d*(sum T_s + T_d) + b) ----------------
__global__ __launch_bounds__(256) void agg128h(
    const u16* __restrict__ T, const int* __restrict__ rowstart, const int* __restrict__ degv,
    const int* __restrict__ csrc, const float* __restrict__ dis, const float* __restrict__ bias,
    u16* __restrict__ OUT, int relu) {
    int node = blockIdx.x * 4 + (threadIdx.x >> 6);
    int l = threadIdx.x & 63;
    int h = l >> 4, c = l & 15;  // 4 edge slots x 16 lanes x 8 feats
    float di = dis[node];
    float acc[8] = {0.f, 0.f, 0.f, 0.f, 0.f, 0.f, 0.f, 0.f};
    if (h == 0) {
        f16x8 s = *(const f16x8*)&T[(long long)node * 128 + c * 8];
#pragma unroll
        for (int i = 0; i < 8; ++i) acc[i] = (float)s[i];
    }
    int e0 = rowstart[node];
    int e1 = e0 + degv[node];
    int e = e0 + h;
    for (; e + 4 < e1; e += 8) {
        int s0 = csrc[e], s1 = csrc[e + 4];
        f16x8 u0 = *(const f16x8*)&T[(long long)s0 * 128 + c * 8];
        f16x8 u1 = *(const f16x8*)&T[(long long)s1 * 128 + c * 8];
#pragma unroll
        for (int i = 0; i < 8; ++i) acc[i] += (float)u0[i] + (float)u1[i];
    }
    if (e < e1) {
        int s0 = csrc[e];
        f16x8 u0 = *(const f16x8*)&T[(long long)s0 * 128 + c * 8];
#pragma unroll
        for (int i = 0; i < 8; ++i) acc[i] += (float)u0[i];
    }
#pragma unroll
    for (int m = 16; m <= 32; m <<= 1) {
#pragma unroll
        for (int i = 0; i < 8; ++i) acc[i] += __shfl_xor(acc[i], m);
    }
    if (h == 0) {
        f32x4 b0 = *(const f32x4*)(bias + c * 8);
        f32x4 b1 = *(const f32x4*)(bias + c * 8 + 4);
        f16x8 r;
#pragma unroll
        for (int i = 0; i < 8; ++i) {
            float b = (i < 4) ? b0[i] : b1[i - 4];
            float v = acc[i] * di + b;
            if (relu) v = fmaxf(v, 0.f);
            r[i] = (_Float16)v;
        }
        *(f16x8*)&OUT[(long long)node * 128 + c * 8] = r;
    }
}

// ---------------- F=32 gather -> fp32 out ----------------
__global__ __launch_bounds__(256) void agg32h(
    const u16* __restrict__ T, const int* __restrict__ rowstart, const int* __restrict__ degv,
    const int* __restrict__ csrc, const float* __restrict__ dis, const float* __restrict__ bias,
    float* __restrict__ OUT) {
    int node = blockIdx.x * 4 + (threadIdx.x >> 6);
    int l = threadIdx.x & 63;
    int h = l >> 3, c = l & 7;  // 8 edge slots x 8 lanes x 4 feats
    float di = dis[node];
    f32x4 acc = (f32x4){0.f, 0.f, 0.f, 0.f};
    if (h == 0) {
        f16x4 s = *(const f16x4*)&T[(long long)node * 32 + c * 4];
#pragma unroll
        for (int i = 0; i < 4; ++i) acc[i] = (float)s[i];
    }
    int e0 = rowstart[node];
    int e1 = e0 + degv[node];
    int e = e0 + h;
    for (; e + 8 < e1; e += 16) {
        int s0 = csrc[e], s1 = csrc[e + 8];
        f16x4 u0 = *(const f16x4*)&T[(long long)s0 * 32 + c * 4];
        f16x4 u1 = *(const f16x4*)&T[(long long)s1 * 32 + c * 4];
#pragma unroll
        for (int i = 0; i < 4; ++i) acc[i] += (float)u0[i] + (float)u1[i];
    }
    if (e < e1) {
        int s0 = csrc[e];
        f16x4 u0 = *(const f16x4*)&T[(long long)s0 * 32 + c * 4];
#pragma unroll
        for (int i = 0; i < 4; ++i) acc[i] += (float)u0[i];
    }
#pragma unroll
    for (int m = 8; m <= 32; m <<= 1) {
#pragma unroll
        for (int i = 0; i < 4; ++i) acc[i] += __shfl_xor(acc[i], m);
    }
    if (h == 0) {
        f32x4 b0 = *(const f32x4*)(bias + c * 4);
        f32x4 r;
#pragma unroll
        for (int i = 0; i < 4; ++i) r[i] = acc[i] * di + b0[i];
        *(f32x4*)(OUT + (long long)node * 32 + c * 4) = r;
    }
}

extern "C" void kernel_launch(void* const* d_in, const int* in_sizes, int n_in,
                              void* d_out, int out_size, void* d_ws, size_t ws_size,
                              hipStream_t stream) {
    const float* x = (const float*)d_in[0];
    const int* ei = (const int*)d_in[1];
    const float* lnw = (const float*)d_in[2];
    const float* lnb = (const float*)d_in[3];
    const float* W1 = (const float*)d_in[4];
    const float* b1 = (const float*)d_in[5];
    const float* W2 = (const float*)d_in[6];
    const float* b2 = (const float*)d_in[7];
    const float* W3 = (const float*)d_in[8];
    const float* b3 = (const float*)d_in[9];
    float* out = (float*)d_out;

    const int n = in_sizes[0] / FIN;  // 65536
    const int E = in_sizes[1] / 2;    // 524288
    const int* src = ei;
    const int* dst = ei + E;

    char* w = (char*)d_ws;
    auto alloc = [&](size_t bytes) {
        char* p = w;
        w += (bytes + 255) & ~(size_t)255;
        return p;
    };
    int* deg = (int*)alloc((size_t)n * 4);
    int* rowstart = (int*)alloc((size_t)n * 4);
    int* erank = (int*)alloc((size_t)E * 4);
    int* total = (int*)alloc(256);
    float* dis = (float*)alloc((size_t)n * 4);
    int* csrc = (int*)alloc((size_t)E * 4);
    u16* w1h = (u16*)alloc(FIN * FH * 2);
    u16* w2h = (u16*)alloc(FH * FH * 2);
    u16* w3h = (u16*)alloc(FH * FZ * 2);
    u16* bufA = (u16*)alloc((size_t)n * FH * 2);
    u16* bufB = (u16*)alloc((size_t)n * FH * 2);

    // ---- dynamic LDS opt-in ----
    const int lds1 = FIN * FH * 2 + 128 * 2 * 4 + 2 * FIN * 4;  // 68608
    const int lds2 = FH * FH * 2;                               // 32768
    const int lds3 = FZ * FH * 2;                               // 8192
    hipFuncSetAttribute((const void*)&gemm_v5<256, 128, true, true>,
                        hipFuncAttributeMaxDynamicSharedMemorySize, lds1);
    hipFuncSetAttribute((const void*)&gemm_v5<128, 128, false, false>,
                        hipFuncAttributeMaxDynamicSharedMemorySize, lds2);
    hipFuncSetAttribute((const void*)&gemm_v5<128, 32, false, false>,
                        hipFuncAttributeMaxDynamicSharedMemorySize, lds3);

    // 1) prep: zero deg/total + weight convert
    prep<<<464, 256, 0, stream>>>(W1, W2, W3, w1h, w2h, w3h, deg, total);
    // 2) degree histogram + edge ranks
    deg_count<<<E / 256, 256, 0, stream>>>(dst, deg, erank, E);
    // 3) single-kernel scan + dis
    scan_fused<<<n / 256, 256, 0, stream>>>(deg, total, rowstart, dis);
    // 4) conv1 GEMM (LN + dis-fold) with head-fused no-atomic csr fill
    gemm_v5<256, 128, true, true><<<n / 128, 512, lds1, stream>>>(
        x, nullptr, w1h, lnw, lnb, dis, bufA, src, dst, erank, rowstart, csrc, E);
    // 5) conv1 aggregate
    agg128h<<<n / 4, 256, 0, stream>>>(bufA, rowstart, deg, csrc, dis, b1, bufB, 1);
    // 6) conv2 GEMM
    gemm_v5<128, 128, false, false><<<n / 128, 512, lds2, stream>>>(
        nullptr, bufB, w2h, nullptr, nullptr, dis, bufA, nullptr, nullptr, nullptr, nullptr, nullptr, 0);
    // 7) conv2 aggregate
    agg128h<<<n / 4, 256, 0, stream>>>(bufA, rowstart, deg, csrc, dis, b2, bufB, 1);
    // 8) conv3 GEMM
    gemm_v5<128, 32, false, false><<<n / 128, 512, lds3, stream>>>(
        nullptr, bufB, w3h, nullptr, nullptr, dis, bufA, nullptr, nullptr, nullptr, nullptr, nullptr, 0);
    // 9) conv3 aggregate -> out
    agg32h<<<n / 4, 256, 0, stream>>>(bufA, rowstart, deg, csrc, dis, b3, out);
}